// Round 12
// baseline (819.086 us; speedup 1.0000x reference)
//
#include <hip/hip_runtime.h>
#include <cmath>

// Problem constants (match reference setup_inputs)
constexpr int N_NODES = 102400;
constexpr int N_EDGES = 1600000;
constexpr int BGR     = 256;     // graphs
constexpr int NPG     = 400;     // nodes per graph
constexpr int F_IN    = 4;
constexpr int H       = 128;
constexpr int GH      = 120;
constexpr int G3      = 360;     // 3*GH
constexpr int C_IN    = 84;
constexpr int LSEQ    = 100;
constexpr int TT      = 19;      // GRU timesteps
constexpr int DHEAD   = 4816;    // 256 + 19*240
constexpr int D1O     = 102;
constexpr int KCOMB   = 256;     // combined K for fused [agg|xin] GEMM
constexpr int CAP     = 64;      // bucket capacity per node
constexpr int NXCD    = 8;
constexpr int NPX     = N_NODES / NXCD;   // 12800 nodes per XCD partition (scatter)
constexpr int SGRP    = 104;              // blocks per XCD group for xcd_scatter
constexpr int NCG     = 8;                // column groups of 16 (bf16 slices, 3.28MB each)
constexpr long SLICE  = (long)N_NODES * 16;   // shorts per cg slice

using short8 = __attribute__((ext_vector_type(8))) short;
using f32x4  = __attribute__((ext_vector_type(4))) float;

__device__ __forceinline__ short f2bf(float f) {      // RNE float->bf16 bits
    unsigned u = __float_as_uint(f);
    u += 0x7FFFu + ((u >> 16) & 1u);
    return (short)(u >> 16);
}
__device__ __forceinline__ float bf2f(short s) {
    return __uint_as_float(((unsigned)(unsigned short)s) << 16);
}

// ---------------- fused small weight prep (5 transposes + 2 bf16 precasts) ----------------
__device__ __forceinline__ void tr_seg(const float* __restrict__ in, float* __restrict__ out,
                                       int R, int C, int i) {
    if (i < R * C) {
        int r = i / C, c = i % C;
        out[(long)c * R + r] = in[i];
    }
}
__device__ __forceinline__ void wbt_seg(const float* __restrict__ Wrel, const float* __restrict__ Wroot,
                                        short* __restrict__ WBT, int i) {
    if (i < H * KCOMB) {
        int h = i >> 8, k = i & 255;
        float v = (k < H) ? Wrel[k * H + h] : Wroot[(k - H) * H + h];
        WBT[h * KCOMB + k] = f2bf(v);
    }
}
constexpr int PB0 = 126;   // Wc   (128,252)T
constexpr int PB1 = 180;   // Wihf (360,128)T
constexpr int PB2 = 180;   // Wihb
constexpr int PB3 = 169;   // Whhf (360,120)T
constexpr int PB4 = 169;   // Whhb
constexpr int PB6 = 128;   // WBT2
constexpr int PB7 = 128;   // WBT3
constexpr int PREP_BLOCKS = PB0+PB1+PB2+PB3+PB4+PB6+PB7;

__global__ void prep_fused(const float* Wc, float* WCT,
                           const float* Wihf, float* WIHTF,
                           const float* Wihb, float* WIHTB,
                           const float* Whhf, float* WHHTF,
                           const float* Whhb, float* WHHTB,
                           const float* W2rel, const float* W2root, short* WBT2,
                           const float* W3rel, const float* W3root, short* WBT3) {
    int b = blockIdx.x;
    int t = threadIdx.x;
    if (b < PB0) { tr_seg(Wc,   WCT,   128, 252, b * 256 + t); return; }  b -= PB0;
    if (b < PB1) { tr_seg(Wihf, WIHTF, G3,  H,   b * 256 + t); return; }  b -= PB1;
    if (b < PB2) { tr_seg(Wihb, WIHTB, G3,  H,   b * 256 + t); return; }  b -= PB2;
    if (b < PB3) { tr_seg(Whhf, WHHTF, G3,  GH,  b * 256 + t); return; }  b -= PB3;
    if (b < PB4) { tr_seg(Whhb, WHHTB, G3,  GH,  b * 256 + t); return; }  b -= PB4;
    if (b < PB6) { wbt_seg(W2rel, W2root, WBT2, b * 256 + t); return; }   b -= PB6;
    wbt_seg(W3rel, W3root, WBT3, b * 256 + t);
}

// ---------------- LDS-tiled transpose for Wd1 (4816,102) -> (102,4816) ----------------
__global__ __launch_bounds__(256) void transpose_tiled(const float* __restrict__ in,
                                                       float* __restrict__ out, int R, int C) {
    __shared__ float tile[32][33];
    const int rb = blockIdx.x * 32, cb = blockIdx.y * 32;
    const int tx = threadIdx.x & 31, ty = threadIdx.x >> 5;   // 32 x 8
#pragma unroll
    for (int yy = 0; yy < 32; yy += 8) {
        int r = rb + ty + yy, c = cb + tx;
        if (r < R && c < C) tile[ty + yy][tx] = in[(long)r * C + c];
    }
    __syncthreads();
#pragma unroll
    for (int yy = 0; yy < 32; yy += 8) {
        int ro = cb + ty + yy, co = rb + tx;
        if (ro < C && co < R) out[(long)ro * R + co] = tile[tx][ty + yy];
    }
}

// ================= XCD-partitioned CSR build (r10-verified) =================
__global__ __launch_bounds__(256) void xcd_scatter(const int* __restrict__ src,
                                                   const int* __restrict__ dst,
                                                   int* __restrict__ cnt,
                                                   int* __restrict__ csr, int E) {
    const int g   = blockIdx.x & (NXCD - 1);
    const int grp = blockIdx.x >> 3;           // 0..SGRP-1
    const int nlo = g * NPX, nhi = nlo + NPX;
    const int stride = SGRP * 256 * 4;
    for (int e = (grp * 256 + threadIdx.x) * 4; e + 3 < E; e += stride) {
        const int4 s = *(const int4*)(src + e);
        const int4 d = *(const int4*)(dst + e);
        if (d.x >= nlo && d.x < nhi) { int p = atomicAdd(&cnt[d.x], 1); csr[((long)d.x << 6) + p] = s.x; }
        if (d.y >= nlo && d.y < nhi) { int p = atomicAdd(&cnt[d.y], 1); csr[((long)d.y << 6) + p] = s.y; }
        if (d.z >= nlo && d.z < nhi) { int p = atomicAdd(&cnt[d.z], 1); csr[((long)d.z << 6) + p] = s.z; }
        if (d.w >= nlo && d.w < nhi) { int p = atomicAdd(&cnt[d.w], 1); csr[((long)d.w << 6) + p] = s.w; }
    }
}

// ================= conv1 (small K) =================
__global__ __launch_bounds__(256) void agg4_csr(const int* __restrict__ cnt,
                                                const int* __restrict__ csr,
                                                const float* __restrict__ x,
                                                float* __restrict__ agg) {
    int i = blockIdx.x * 256 + threadIdx.x;     // over N*4
    int n = i >> 2, c = i & 3;
    const int cn = cnt[n];
    const int* idx = csr + ((long)n << 6);
    float acc = 0.f;
    for (int j = 0; j < cn; ++j) acc += x[(long)idx[j] * 4 + c];
    agg[i] = acc;
}

// conv1 transform: fp32 out (residual src) + bf16 copy in cg-major layout [8][N][16]
__global__ void gc1_transform(const float* __restrict__ agg4, const float* __restrict__ x,
                              const float* __restrict__ Wrel, const float* __restrict__ Wroot,
                              const float* __restrict__ bias, float* __restrict__ out,
                              short* __restrict__ outb) {
    long i = (long)blockIdx.x * 256 + threadIdx.x;   // over N*H
    int h = (int)(i & (H - 1));
    long n = i >> 7;
    const float4 a  = *(const float4*)(agg4 + n * 4);
    const float4 xv = *(const float4*)(x    + n * 4);
    float acc = bias[h]
        + a.x  * Wrel[0 * H + h] + a.y  * Wrel[1 * H + h]
        + a.z  * Wrel[2 * H + h] + a.w  * Wrel[3 * H + h]
        + xv.x * Wroot[0 * H + h] + xv.y * Wroot[1 * H + h]
        + xv.z * Wroot[2 * H + h] + xv.w * Wroot[3 * H + h];
    float v = fmaxf(acc, 0.f);
    out[i] = v;
    outb[(long)(h >> 4) * SLICE + n * 16 + (h & 15)] = f2bf(v);
}

// ================= cg-sliced bf16 gather: slice cg (3.28MB) stays L2-local =================
// grid = NCG * (N/128); cg = blockIdx&7 -> round-robin lands all slice-g blocks on XCD g.
// 2 lanes per node (short8 = 8 cols each); 128 nodes per block.
__global__ __launch_bounds__(256) void agg128_cg(const int* __restrict__ cnt,
                                                 const int* __restrict__ csr,
                                                 const short* __restrict__ xb,
                                                 short* __restrict__ aggb) {
    const int cg = blockIdx.x & (NCG - 1);
    const int nb = blockIdx.x >> 3;
    const int n  = nb * 128 + (threadIdx.x >> 1);
    const int lane = threadIdx.x & 1;           // 8 bf16 cols each
    const int cn = cnt[n];
    const int* idx = csr + ((long)n << 6);
    const short* xs = xb + (long)cg * SLICE + lane * 8;
    float acc[8];
#pragma unroll
    for (int q = 0; q < 8; ++q) acc[q] = 0.f;
    int j = 0;
    for (; j + 3 < cn; j += 4) {
        const int4 ii = *(const int4*)(idx + j);
        const short8 r0 = *(const short8*)(xs + (long)ii.x * 16);
        const short8 r1 = *(const short8*)(xs + (long)ii.y * 16);
        const short8 r2 = *(const short8*)(xs + (long)ii.z * 16);
        const short8 r3 = *(const short8*)(xs + (long)ii.w * 16);
#pragma unroll
        for (int q = 0; q < 8; ++q)
            acc[q] += (bf2f(r0[q]) + bf2f(r1[q])) + (bf2f(r2[q]) + bf2f(r3[q]));
    }
    for (; j < cn; ++j) {
        const short8 r0 = *(const short8*)(xs + (long)idx[j] * 16);
#pragma unroll
        for (int q = 0; q < 8; ++q) acc[q] += bf2f(r0[q]);
    }
    short8 o;
#pragma unroll
    for (int q = 0; q < 8; ++q) o[q] = f2bf(acc[q]);
    *(short8*)(aggb + (long)cg * SLICE + (long)n * 16 + lane * 8) = o;
}

// ---------------- GraphConv node transform via bf16 MFMA (cg-major A operands) ----------------
template <int RES, int OUTF, int OUTB>
__global__ __launch_bounds__(256) void gc_mfma(
        const short* __restrict__ aggb, const short* __restrict__ xinb,
        const short* __restrict__ WBT, const float* __restrict__ bias,
        const float* __restrict__ res, float* __restrict__ outf,
        short* __restrict__ outb) {
    const int wid   = threadIdx.x >> 6;     // 0..3
    const int lane  = threadIdx.x & 63;
    const int l15   = lane & 15;
    const int kslot = lane >> 4;            // 0..3
    const long n0   = (long)blockIdx.x * 128 + wid * 32;

    f32x4 acc[2][8];
#pragma unroll
    for (int i = 0; i < 2; ++i)
#pragma unroll
        for (int j = 0; j < 8; ++j) acc[i][j] = (f32x4){0.f, 0.f, 0.f, 0.f};

#pragma unroll
    for (int ks = 0; ks < 8; ++ks) {        // combined-k step of 32
        const short* srcb = (ks < 4) ? aggb : xinb;
        const int koff = (ks < 4 ? ks * 32 : (ks - 4) * 32) + kslot * 8;
        const short* sbase = srcb + (long)(koff >> 4) * SLICE + (koff & 15);
        short8 afr[2];
#pragma unroll
        for (int rt = 0; rt < 2; ++rt)
            afr[rt] = *(const short8*)(sbase + (n0 + rt * 16 + l15) * 16);
        const int kb = ks * 32 + kslot * 8;
        short8 bfr[8];
#pragma unroll
        for (int ct = 0; ct < 8; ++ct)
            bfr[ct] = *(const short8*)(WBT + (long)(ct * 16 + l15) * KCOMB + kb);
#pragma unroll
        for (int rt = 0; rt < 2; ++rt)
#pragma unroll
            for (int ct = 0; ct < 8; ++ct)
                acc[rt][ct] = __builtin_amdgcn_mfma_f32_16x16x32_bf16(
                    afr[rt], bfr[ct], acc[rt][ct], 0, 0, 0);
    }

#pragma unroll
    for (int rt = 0; rt < 2; ++rt) {
        const long rbase = n0 + rt * 16 + kslot * 4;
#pragma unroll
        for (int ct = 0; ct < 8; ++ct) {
            const int h = ct * 16 + l15;
            const float bv = bias[h];
#pragma unroll
            for (int r = 0; r < 4; ++r) {
                const long rowi = rbase + r;
                float v = fmaxf(acc[rt][ct][r] + bv, 0.f);
                if (RES) v += res[rowi * H + h];
                if (OUTF) outf[rowi * H + h] = v;
                if (OUTB) outb[(long)ct * SLICE + rowi * 16 + l15] = f2bf(v);
            }
        }
    }
}

// ---------------- graph max/mean pool -> xc[:, 0:256] ----------------
__global__ __launch_bounds__(512) void pool_kernel(const float* __restrict__ x4, float* __restrict__ xc) {
    int g = blockIdx.x;
    int h = threadIdx.x & 127;
    int part = threadIdx.x >> 7;        // 0..3 (100 nodes each)
    const float* base = x4 + ((long)g * NPG + part * 100) * H + h;
    float mx = -INFINITY, sm = 0.f;
#pragma unroll 4
    for (int i = 0; i < 100; ++i) {
        float v = base[(long)i * H];
        mx = fmaxf(mx, v);
        sm += v;
    }
    __shared__ float smx[4][128], ssm[4][128];
    smx[part][h] = mx; ssm[part][h] = sm;
    __syncthreads();
    if (part == 0) {
        float m = fmaxf(fmaxf(smx[0][h], smx[1][h]), fmaxf(smx[2][h], smx[3][h]));
        float s = ssm[0][h] + ssm[1][h] + ssm[2][h] + ssm[3][h];
        xc[(long)g * DHEAD + h] = m;
        xc[(long)g * DHEAD + H + h] = s * (1.f / NPG);
    }
}

// ---------------- conv1d(84->128,k=3) + relu + avgpool5 -> xs[t][b][o] ----------------
__global__ __launch_bounds__(128) void conv1d_pool(const float* __restrict__ in,
                                                   const float* __restrict__ WcT,
                                                   const float* __restrict__ bc,
                                                   float* __restrict__ xs) {
    int p = blockIdx.x;    // 0..18
    int b = blockIdx.y;    // 0..255
    int o = threadIdx.x;   // 0..127
    __shared__ float sIn[C_IN][8];
    const float* ib = in + (long)b * C_IN * LSEQ;
    for (int idx = threadIdx.x; idx < C_IN * 7; idx += 128) {
        int c = idx / 7, j = idx % 7;
        sIn[c][j] = ib[c * LSEQ + 5 * p + j];
    }
    __syncthreads();
    float a0 = 0, a1 = 0, a2 = 0, a3 = 0, a4 = 0;
    for (int c = 0; c < C_IN; ++c) {
        float i0 = sIn[c][0], i1 = sIn[c][1], i2 = sIn[c][2], i3 = sIn[c][3];
        float i4 = sIn[c][4], i5 = sIn[c][5], i6 = sIn[c][6];
        float w0 = WcT[(c * 3 + 0) * H + o];
        float w1 = WcT[(c * 3 + 1) * H + o];
        float w2 = WcT[(c * 3 + 2) * H + o];
        a0 += w0 * i0 + w1 * i1 + w2 * i2;
        a1 += w0 * i1 + w1 * i2 + w2 * i3;
        a2 += w0 * i2 + w1 * i3 + w2 * i4;
        a3 += w0 * i3 + w1 * i4 + w2 * i5;
        a4 += w0 * i4 + w1 * i5 + w2 * i6;
    }
    float bcv = bc[o];
    float r = fmaxf(a0 + bcv, 0.f) + fmaxf(a1 + bcv, 0.f) + fmaxf(a2 + bcv, 0.f)
            + fmaxf(a3 + bcv, 0.f) + fmaxf(a4 + bcv, 0.f);
    xs[((long)p * BGR + b) * H + o] = r * 0.2f;
}

// ---------------- gi = xs @ WihT + bih  (16 rows/block) ----------------
__global__ __launch_bounds__(384) void gi_gemm(const float* __restrict__ xs,
                                               const float* __restrict__ WihT,
                                               const float* __restrict__ bih,
                                               float* __restrict__ gi) {
    const long r0 = (long)blockIdx.x * 16;
    const int g = threadIdx.x;
    __shared__ __align__(16) float sX[16][H];
    for (int idx = threadIdx.x; idx < 16 * H; idx += 384)
        sX[idx >> 7][idx & (H - 1)] = xs[r0 * H + idx];
    __syncthreads();
    if (g >= G3) return;
    const float bv = bih[g];
    float acc[16];
#pragma unroll
    for (int r = 0; r < 16; ++r) acc[r] = bv;
    for (int k = 0; k < H; k += 4) {
        float w0 = WihT[(k + 0) * G3 + g], w1 = WihT[(k + 1) * G3 + g];
        float w2 = WihT[(k + 2) * G3 + g], w3 = WihT[(k + 3) * G3 + g];
#pragma unroll
        for (int r = 0; r < 16; ++r) {
            float4 xv = *(const float4*)&sX[r][k];
            acc[r] += xv.x * w0 + xv.y * w1 + xv.z * w2 + xv.w * w3;
        }
    }
#pragma unroll
    for (int r = 0; r < 16; ++r)
        gi[(r0 + r) * G3 + g] = acc[r];
}

// ---------------- full BiGRU recurrence ----------------
__device__ __forceinline__ float sigmoidf_(float x) { return 1.f / (1.f + expf(-x)); }

__global__ __launch_bounds__(384) void gru_kernel(
        const float* __restrict__ giF, const float* __restrict__ giB,
        const float* __restrict__ WhhTF, const float* __restrict__ WhhTB,
        const float* __restrict__ bhhF, const float* __restrict__ bhhB,
        float* __restrict__ xc) {
    const int b = blockIdx.x & (BGR - 1);
    const int dir = blockIdx.x >> 8;
    const float* gi   = dir ? giB : giF;
    const float* WhhT = dir ? WhhTB : WhhTF;
    const float* bhh  = dir ? bhhB : bhhF;
    const int g = threadIdx.x;
    const int gc = g < G3 ? g : (G3 - 1);

    float w[GH];
#pragma unroll
    for (int k = 0; k < GH; ++k) w[k] = WhhT[(long)k * G3 + gc];
    const float bh = bhh[gc];

    __shared__ __align__(16) float sh[GH];
    __shared__ float sgh[G3];
    if (g < GH) sh[g] = 0.f;
    __syncthreads();

    for (int tt = 0; tt < TT; ++tt) {
        const int t = dir ? (TT - 1 - tt) : tt;
        float acc = bh;
#pragma unroll
        for (int k4 = 0; k4 < GH / 4; ++k4) {
            float4 hv = *(const float4*)&sh[k4 * 4];
            acc += hv.x * w[k4 * 4] + hv.y * w[k4 * 4 + 1]
                 + hv.z * w[k4 * 4 + 2] + hv.w * w[k4 * 4 + 3];
        }
        if (g < G3) sgh[g] = acc;
        __syncthreads();
        if (g < GH) {
            const float* gib = gi + ((long)t * BGR + b) * G3;
            float r = sigmoidf_(gib[g] + sgh[g]);
            float z = sigmoidf_(gib[GH + g] + sgh[GH + g]);
            float n = tanhf(gib[2 * GH + g] + r * sgh[2 * GH + g]);
            float h2 = (1.f - z) * n + z * sh[g];
            sh[g] = h2;
            xc[(long)b * DHEAD + 256 + t * 240 + dir * GH + g] = h2;
        }
        __syncthreads();
    }
}

// ---------------- dense head: wave = 4 j x 8 b tile ----------------
__global__ __launch_bounds__(256) void dense1(const float* __restrict__ xc,
                                              const float* __restrict__ Wd1T,
                                              const float* __restrict__ bd1,
                                              float* __restrict__ d1) {
    const int wid  = blockIdx.x * 4 + (threadIdx.x >> 6);   // 0 .. 26*32-1
    const int lane = threadIdx.x & 63;
    const int jg = wid % 26;    // 26 groups of 4 j (104 >= 102)
    const int bg = wid / 26;    // 32 groups of 8 b
    const int j0 = jg * 4, b0 = bg * 8;

    float acc[4][8];
#pragma unroll
    for (int jj = 0; jj < 4; ++jj)
#pragma unroll
        for (int bb = 0; bb < 8; ++bb) acc[jj][bb] = 0.f;

    for (int i = lane; i < DHEAD / 4; i += 64) {
        float4 wv[4], xv[8];
#pragma unroll
        for (int jj = 0; jj < 4; ++jj) {
            int j = j0 + jj; if (j > D1O - 1) j = D1O - 1;
            wv[jj] = *(const float4*)(Wd1T + (long)j * DHEAD + i * 4);
        }
#pragma unroll
        for (int bb = 0; bb < 8; ++bb)
            xv[bb] = *(const float4*)(xc + (long)(b0 + bb) * DHEAD + i * 4);
#pragma unroll
        for (int jj = 0; jj < 4; ++jj)
#pragma unroll
            for (int bb = 0; bb < 8; ++bb)
                acc[jj][bb] += wv[jj].x * xv[bb].x + wv[jj].y * xv[bb].y
                             + wv[jj].z * xv[bb].z + wv[jj].w * xv[bb].w;
    }
#pragma unroll
    for (int m = 32; m >= 1; m >>= 1)
#pragma unroll
        for (int jj = 0; jj < 4; ++jj)
#pragma unroll
            for (int bb = 0; bb < 8; ++bb)
                acc[jj][bb] += __shfl_xor(acc[jj][bb], m, 64);
    if (lane < 32) {
        const int jj = lane >> 3, bb = lane & 7;
        const int j = j0 + jj;
        if (j < D1O)
            d1[(long)(b0 + bb) * D1O + j] = fmaxf(acc[jj][bb] + bd1[j], 0.f);
    }
}

__global__ void final_head(const float* __restrict__ d1, const float* __restrict__ Wd3,
                           const float* __restrict__ bd3, float* __restrict__ out) {
    int b = threadIdx.x;   // 256 threads, 1 block
    if (b >= BGR) return;
    float v0 = bd3[0], v1 = bd3[1];
    for (int k = 0; k < D1O; ++k) {
        float xv = d1[(long)b * D1O + k];
        v0 += xv * Wd3[k * 2 + 0];
        v1 += xv * Wd3[k * 2 + 1];
    }
    float m = fmaxf(v0, v1);
    float lse = m + logf(expf(v0 - m) + expf(v1 - m));
    out[b * 2 + 0] = v0 - lse;
    out[b * 2 + 1] = v1 - lse;
}

// ---------------- launch ----------------
extern "C" void kernel_launch(void* const* d_in, const int* in_sizes, int n_in,
                              void* d_out, int out_size, void* d_ws, size_t ws_size,
                              hipStream_t stream) {
    const float* x      = (const float*)d_in[0];
    const int*   ei     = (const int*)d_in[1];
    const float* tgt    = (const float*)d_in[3];
    const float* W1rel  = (const float*)d_in[4];
    const float* W1root = (const float*)d_in[5];
    const float* b1     = (const float*)d_in[6];
    const float* W2rel  = (const float*)d_in[7];
    const float* W2root = (const float*)d_in[8];
    const float* b2     = (const float*)d_in[9];
    const float* W3rel  = (const float*)d_in[10];
    const float* W3root = (const float*)d_in[11];
    const float* b3     = (const float*)d_in[12];
    const float* Wc     = (const float*)d_in[13];
    const float* bc     = (const float*)d_in[14];
    const float* Wih_f  = (const float*)d_in[15];
    const float* Whh_f  = (const float*)d_in[16];
    const float* bih_f  = (const float*)d_in[17];
    const float* bhh_f  = (const float*)d_in[18];
    const float* Wih_b  = (const float*)d_in[19];
    const float* Whh_b  = (const float*)d_in[20];
    const float* bih_b  = (const float*)d_in[21];
    const float* bhh_b  = (const float*)d_in[22];
    const float* Wd1    = (const float*)d_in[23];
    const float* bd1    = (const float*)d_in[24];
    const float* Wd3    = (const float*)d_in[25];
    const float* bd3    = (const float*)d_in[26];

    const int* srcI = ei;
    const int* dstI = ei + N_EDGES;

    // workspace layout (floats)
    float* ws = (float*)d_ws;
    size_t off = 0;
    float* AGG4  = ws + off; off += (size_t)N_NODES * 4;
    float* X1    = ws + off; off += (size_t)N_NODES * H;   // fp32: residual src, conv4 out
    float* XS    = ws + off; off += (size_t)TT * BGR * H;
    float* GIF   = ws + off; off += (size_t)TT * BGR * G3;
    float* GIB   = ws + off; off += (size_t)TT * BGR * G3;
    float* XC    = ws + off; off += (size_t)BGR * DHEAD;
    float* D1    = ws + off; off += (size_t)BGR * D1O + 2;
    float* WCT   = ws + off; off += (size_t)C_IN * 3 * H;
    float* WIHTF = ws + off; off += (size_t)H * G3;
    float* WIHTB = ws + off; off += (size_t)H * G3;
    float* WHHTF = ws + off; off += (size_t)GH * G3;
    float* WHHTB = ws + off; off += (size_t)GH * G3;
    float* WD1T  = ws + off; off += (size_t)DHEAD * D1O;
    off = (off + 3) & ~(size_t)3;                       // 16B align
    short* WBT2  = (short*)(ws + off); off += (size_t)H * KCOMB / 2;   // bf16 [128][256]
    short* WBT3  = (short*)(ws + off); off += (size_t)H * KCOMB / 2;
    short* AGGB  = (short*)(ws + off); off += (size_t)N_NODES * H / 2; // bf16 agg  (cg-major)
    short* X1B   = (short*)(ws + off); off += (size_t)N_NODES * H / 2; // bf16 x1   (cg-major)
    short* X2B   = (short*)(ws + off); off += (size_t)N_NODES * H / 2; // bf16 x2   (cg-major)
    short* X3B   = (short*)(ws + off); off += (size_t)N_NODES * H / 2; // bf16 x3   (cg-major)
    // int region
    int* ibase   = (int*)(ws + off);
    int* CNT     = ibase;                     // N
    int* CSR     = ibase + N_NODES;           // N * CAP

    // weight prep
    prep_fused<<<PREP_BLOCKS, 256, 0, stream>>>(Wc, WCT, Wih_f, WIHTF, Wih_b, WIHTB,
                                                Whh_f, WHHTF, Whh_b, WHHTB,
                                                W2rel, W2root, WBT2, W3rel, W3root, WBT3);
    transpose_tiled<<<dim3((DHEAD + 31) / 32, (D1O + 31) / 32), 256, 0, stream>>>(Wd1, WD1T, DHEAD, D1O);

    // ---- XCD-partitioned CSR build ----
    hipMemsetAsync(CNT, 0, (size_t)N_NODES * sizeof(int), stream);
    xcd_scatter<<<NXCD * SGRP, 256, 0, stream>>>(srcI, dstI, CNT, CSR, N_EDGES);

    // conv1: x (N,4) -> x1 (N,128) fp32 + bf16 cg-major copy
    agg4_csr<<<(N_NODES * 4) / 256, 256, 0, stream>>>(CNT, CSR, x, AGG4);
    gc1_transform<<<(N_NODES * H) / 256, 256, 0, stream>>>(AGG4, x, W1rel, W1root, b1, X1, X1B);

    // conv2: x1 -> x2 (bf16 cg-major)
    agg128_cg<<<NCG * (N_NODES / 128), 256, 0, stream>>>(CNT, CSR, X1B, AGGB);
    gc_mfma<0, 0, 1><<<N_NODES / 128, 256, 0, stream>>>(AGGB, X1B, WBT2, b2, nullptr, nullptr, X2B);

    // conv3: x2 -> x3 (bf16 cg-major), + residual x1 (fp32)
    agg128_cg<<<NCG * (N_NODES / 128), 256, 0, stream>>>(CNT, CSR, X2B, AGGB);
    gc_mfma<1, 0, 1><<<N_NODES / 128, 256, 0, stream>>>(AGGB, X2B, WBT3, b3, X1, nullptr, X3B);

    // conv4: x3 -> x4 (fp32, reuses X1; residual read of X1 finished in conv3)
    agg128_cg<<<NCG * (N_NODES / 128), 256, 0, stream>>>(CNT, CSR, X3B, AGGB);
    gc_mfma<0, 1, 0><<<N_NODES / 128, 256, 0, stream>>>(AGGB, X3B, WBT3, b3, nullptr, X1, nullptr);

    // pooling -> xc[:, 0:256]
    pool_kernel<<<BGR, 512, 0, stream>>>(X1, XC);

    // conv1d + relu + avgpool -> xs
    conv1d_pool<<<dim3(TT, BGR), 128, 0, stream>>>(tgt, WCT, bc, XS);

    // gi GEMMs (16 rows/block)
    gi_gemm<<<(TT * BGR) / 16, 384, 0, stream>>>(XS, WIHTF, bih_f, GIF);
    gi_gemm<<<(TT * BGR) / 16, 384, 0, stream>>>(XS, WIHTB, bih_b, GIB);

    // BiGRU -> xc[:, 256:4816]
    gru_kernel<<<2 * BGR, 384, 0, stream>>>(GIF, GIB, WHHTF, WHHTB, bhh_f, bhh_b, XC);

    // dense head
    dense1<<<(26 * 32) / 4, 256, 0, stream>>>(XC, WD1T, bd1, D1);
    final_head<<<1, 256, 0, stream>>>(D1, Wd3, bd3, (float*)d_out);
}

// Round 13
// 709.566 us; speedup vs baseline: 1.1543x; 1.1543x over previous
//
#include <hip/hip_runtime.h>
#include <cmath>

// Problem constants (match reference setup_inputs)
constexpr int N_NODES = 102400;
constexpr int N_EDGES = 1600000;
constexpr int BGR     = 256;     // graphs
constexpr int NPG     = 400;     // nodes per graph
constexpr int F_IN    = 4;
constexpr int H       = 128;
constexpr int GH      = 120;
constexpr int G3      = 360;     // 3*GH
constexpr int C_IN    = 84;
constexpr int LSEQ    = 100;
constexpr int TT      = 19;      // GRU timesteps
constexpr int DHEAD   = 4816;    // 256 + 19*240
constexpr int D1O     = 102;
constexpr int KCOMB   = 256;     // combined K for fused [agg|xin] GEMM
constexpr int CAP     = 64;      // bucket capacity per node
constexpr int NXCD    = 8;
constexpr int NPX     = N_NODES / NXCD;   // 12800 nodes per XCD partition (scatter)
constexpr int SGRP    = 104;              // blocks per XCD group for xcd_scatter

using short8 = __attribute__((ext_vector_type(8))) short;
using f32x4  = __attribute__((ext_vector_type(4))) float;

__device__ __forceinline__ short f2bf(float f) {      // RNE float->bf16 bits
    unsigned u = __float_as_uint(f);
    u += 0x7FFFu + ((u >> 16) & 1u);
    return (short)(u >> 16);
}
__device__ __forceinline__ float bf2f(short s) {
    return __uint_as_float(((unsigned)(unsigned short)s) << 16);
}

// ---------------- fused small weight prep (5 transposes + 2 bf16 precasts) ----------------
__device__ __forceinline__ void tr_seg(const float* __restrict__ in, float* __restrict__ out,
                                       int R, int C, int i) {
    if (i < R * C) {
        int r = i / C, c = i % C;
        out[(long)c * R + r] = in[i];
    }
}
__device__ __forceinline__ void wbt_seg(const float* __restrict__ Wrel, const float* __restrict__ Wroot,
                                        short* __restrict__ WBT, int i) {
    if (i < H * KCOMB) {
        int h = i >> 8, k = i & 255;
        float v = (k < H) ? Wrel[k * H + h] : Wroot[(k - H) * H + h];
        WBT[h * KCOMB + k] = f2bf(v);
    }
}
constexpr int PB0 = 126;   // Wc   (128,252)T
constexpr int PB1 = 180;   // Wihf (360,128)T
constexpr int PB2 = 180;   // Wihb
constexpr int PB3 = 169;   // Whhf (360,120)T
constexpr int PB4 = 169;   // Whhb
constexpr int PB6 = 128;   // WBT2
constexpr int PB7 = 128;   // WBT3
constexpr int PREP_BLOCKS = PB0+PB1+PB2+PB3+PB4+PB6+PB7;

__global__ void prep_fused(const float* Wc, float* WCT,
                           const float* Wihf, float* WIHTF,
                           const float* Wihb, float* WIHTB,
                           const float* Whhf, float* WHHTF,
                           const float* Whhb, float* WHHTB,
                           const float* W2rel, const float* W2root, short* WBT2,
                           const float* W3rel, const float* W3root, short* WBT3) {
    int b = blockIdx.x;
    int t = threadIdx.x;
    if (b < PB0) { tr_seg(Wc,   WCT,   128, 252, b * 256 + t); return; }  b -= PB0;
    if (b < PB1) { tr_seg(Wihf, WIHTF, G3,  H,   b * 256 + t); return; }  b -= PB1;
    if (b < PB2) { tr_seg(Wihb, WIHTB, G3,  H,   b * 256 + t); return; }  b -= PB2;
    if (b < PB3) { tr_seg(Whhf, WHHTF, G3,  GH,  b * 256 + t); return; }  b -= PB3;
    if (b < PB4) { tr_seg(Whhb, WHHTB, G3,  GH,  b * 256 + t); return; }  b -= PB4;
    if (b < PB6) { wbt_seg(W2rel, W2root, WBT2, b * 256 + t); return; }   b -= PB6;
    wbt_seg(W3rel, W3root, WBT3, b * 256 + t);
}

// ---------------- LDS-tiled transpose for Wd1 (4816,102) -> (102,4816) ----------------
__global__ __launch_bounds__(256) void transpose_tiled(const float* __restrict__ in,
                                                       float* __restrict__ out, int R, int C) {
    __shared__ float tile[32][33];
    const int rb = blockIdx.x * 32, cb = blockIdx.y * 32;
    const int tx = threadIdx.x & 31, ty = threadIdx.x >> 5;   // 32 x 8
#pragma unroll
    for (int yy = 0; yy < 32; yy += 8) {
        int r = rb + ty + yy, c = cb + tx;
        if (r < R && c < C) tile[ty + yy][tx] = in[(long)r * C + c];
    }
    __syncthreads();
#pragma unroll
    for (int yy = 0; yy < 32; yy += 8) {
        int ro = cb + ty + yy, co = rb + tx;
        if (ro < C && co < R) out[(long)ro * R + co] = tile[tx][ty + yy];
    }
}

// ================= XCD-partitioned CSR build (r10-verified) =================
__global__ __launch_bounds__(256) void xcd_scatter(const int* __restrict__ src,
                                                   const int* __restrict__ dst,
                                                   int* __restrict__ cnt,
                                                   int* __restrict__ csr, int E) {
    const int g   = blockIdx.x & (NXCD - 1);
    const int grp = blockIdx.x >> 3;           // 0..SGRP-1
    const int nlo = g * NPX, nhi = nlo + NPX;
    const int stride = SGRP * 256 * 4;
    for (int e = (grp * 256 + threadIdx.x) * 4; e + 3 < E; e += stride) {
        const int4 s = *(const int4*)(src + e);
        const int4 d = *(const int4*)(dst + e);
        if (d.x >= nlo && d.x < nhi) { int p = atomicAdd(&cnt[d.x], 1); csr[((long)d.x << 6) + p] = s.x; }
        if (d.y >= nlo && d.y < nhi) { int p = atomicAdd(&cnt[d.y], 1); csr[((long)d.y << 6) + p] = s.y; }
        if (d.z >= nlo && d.z < nhi) { int p = atomicAdd(&cnt[d.z], 1); csr[((long)d.z << 6) + p] = s.z; }
        if (d.w >= nlo && d.w < nhi) { int p = atomicAdd(&cnt[d.w], 1); csr[((long)d.w << 6) + p] = s.w; }
    }
}

// ================= conv1 (small K) =================
__global__ __launch_bounds__(256) void agg4_csr(const int* __restrict__ cnt,
                                                const int* __restrict__ csr,
                                                const float* __restrict__ x,
                                                float* __restrict__ agg) {
    int i = blockIdx.x * 256 + threadIdx.x;     // over N*4
    int n = i >> 2, c = i & 3;
    const int cn = cnt[n];
    const int* idx = csr + ((long)n << 6);
    float acc = 0.f;
    for (int j = 0; j < cn; ++j) acc += x[(long)idx[j] * 4 + c];
    agg[i] = acc;
}

// conv1 transform: fp32 out (residual source) + bf16 copy (conv2 gather/root)
__global__ void gc1_transform(const float* __restrict__ agg4, const float* __restrict__ x,
                              const float* __restrict__ Wrel, const float* __restrict__ Wroot,
                              const float* __restrict__ bias, float* __restrict__ out,
                              short* __restrict__ outb) {
    long i = (long)blockIdx.x * 256 + threadIdx.x;   // over N*H
    int h = (int)(i & (H - 1));
    long n = i >> 7;
    const float4 a  = *(const float4*)(agg4 + n * 4);
    const float4 xv = *(const float4*)(x    + n * 4);
    float acc = bias[h]
        + a.x  * Wrel[0 * H + h] + a.y  * Wrel[1 * H + h]
        + a.z  * Wrel[2 * H + h] + a.w  * Wrel[3 * H + h]
        + xv.x * Wroot[0 * H + h] + xv.y * Wroot[1 * H + h]
        + xv.z * Wroot[2 * H + h] + xv.w * Wroot[3 * H + h];
    float v = fmaxf(acc, 0.f);
    out[i] = v;
    outb[i] = f2bf(v);
}

// ================= bf16 CSR gather (H=128), 8-deep unroll for MLP =================
// r12 lesson: cg-slicing worsened line utilization (32B of 64B lines) + 8x idx re-read;
// full 256B-row gather consumes every fetched line. 8 loads in flight per thread.
__global__ __launch_bounds__(256) void agg128_bf(const int* __restrict__ cnt,
                                                 const int* __restrict__ csr,
                                                 const short* __restrict__ xb,
                                                 short* __restrict__ aggb) {
    const int lane = threadIdx.x & 15;          // 8 bf16 columns each
    const int n = blockIdx.x * 16 + (threadIdx.x >> 4);
    const int cn = cnt[n];
    const int* idx = csr + ((long)n << 6);
    const short* xs = xb + lane * 8;
    float acc[8];
#pragma unroll
    for (int q = 0; q < 8; ++q) acc[q] = 0.f;
    int j = 0;
    for (; j + 7 < cn; j += 8) {
        const int4 i0 = *(const int4*)(idx + j);
        const int4 i1 = *(const int4*)(idx + j + 4);
        const short8 r0 = *(const short8*)(xs + (long)i0.x * H);
        const short8 r1 = *(const short8*)(xs + (long)i0.y * H);
        const short8 r2 = *(const short8*)(xs + (long)i0.z * H);
        const short8 r3 = *(const short8*)(xs + (long)i0.w * H);
        const short8 r4 = *(const short8*)(xs + (long)i1.x * H);
        const short8 r5 = *(const short8*)(xs + (long)i1.y * H);
        const short8 r6 = *(const short8*)(xs + (long)i1.z * H);
        const short8 r7 = *(const short8*)(xs + (long)i1.w * H);
#pragma unroll
        for (int q = 0; q < 8; ++q)
            acc[q] += ((bf2f(r0[q]) + bf2f(r1[q])) + (bf2f(r2[q]) + bf2f(r3[q])))
                    + ((bf2f(r4[q]) + bf2f(r5[q])) + (bf2f(r6[q]) + bf2f(r7[q])));
    }
    for (; j + 3 < cn; j += 4) {
        const int4 ii = *(const int4*)(idx + j);
        const short8 r0 = *(const short8*)(xs + (long)ii.x * H);
        const short8 r1 = *(const short8*)(xs + (long)ii.y * H);
        const short8 r2 = *(const short8*)(xs + (long)ii.z * H);
        const short8 r3 = *(const short8*)(xs + (long)ii.w * H);
#pragma unroll
        for (int q = 0; q < 8; ++q)
            acc[q] += (bf2f(r0[q]) + bf2f(r1[q])) + (bf2f(r2[q]) + bf2f(r3[q]));
    }
    for (; j < cn; ++j) {
        const short8 r0 = *(const short8*)(xs + (long)idx[j] * H);
#pragma unroll
        for (int q = 0; q < 8; ++q) acc[q] += bf2f(r0[q]);
    }
    short8 o;
#pragma unroll
    for (int q = 0; q < 8; ++q) o[q] = f2bf(acc[q]);
    *(short8*)(aggb + (long)n * H + lane * 8) = o;
}

// ---------------- GraphConv node transform via bf16 MFMA ----------------
template <int RES, int OUTF, int OUTB>
__global__ __launch_bounds__(256) void gc_mfma(
        const short* __restrict__ aggb, const short* __restrict__ xinb,
        const short* __restrict__ WBT, const float* __restrict__ bias,
        const float* __restrict__ res, float* __restrict__ outf,
        short* __restrict__ outb) {
    const int wid   = threadIdx.x >> 6;     // 0..3
    const int lane  = threadIdx.x & 63;
    const int l15   = lane & 15;
    const int kslot = lane >> 4;            // 0..3
    const long n0   = (long)blockIdx.x * 128 + wid * 32;

    f32x4 acc[2][8];
#pragma unroll
    for (int i = 0; i < 2; ++i)
#pragma unroll
        for (int j = 0; j < 8; ++j) acc[i][j] = (f32x4){0.f, 0.f, 0.f, 0.f};

#pragma unroll
    for (int ks = 0; ks < 8; ++ks) {        // combined-k step of 32
        const short* srcb = (ks < 4) ? aggb : xinb;
        const int koff = (ks < 4 ? ks * 32 : (ks - 4) * 32) + kslot * 8;
        short8 afr[2];
#pragma unroll
        for (int rt = 0; rt < 2; ++rt)
            afr[rt] = *(const short8*)(srcb + (n0 + rt * 16 + l15) * H + koff);
        const int kb = ks * 32 + kslot * 8;
        short8 bfr[8];
#pragma unroll
        for (int ct = 0; ct < 8; ++ct)
            bfr[ct] = *(const short8*)(WBT + (long)(ct * 16 + l15) * KCOMB + kb);
#pragma unroll
        for (int rt = 0; rt < 2; ++rt)
#pragma unroll
            for (int ct = 0; ct < 8; ++ct)
                acc[rt][ct] = __builtin_amdgcn_mfma_f32_16x16x32_bf16(
                    afr[rt], bfr[ct], acc[rt][ct], 0, 0, 0);
    }

#pragma unroll
    for (int rt = 0; rt < 2; ++rt) {
        const long rbase = n0 + rt * 16 + kslot * 4;
#pragma unroll
        for (int ct = 0; ct < 8; ++ct) {
            const int h = ct * 16 + l15;
            const float bv = bias[h];
#pragma unroll
            for (int r = 0; r < 4; ++r) {
                const long rowi = rbase + r;
                float v = fmaxf(acc[rt][ct][r] + bv, 0.f);
                if (RES) v += res[rowi * H + h];
                if (OUTF) outf[rowi * H + h] = v;
                if (OUTB) outb[rowi * H + h] = f2bf(v);
            }
        }
    }
}

// ---------------- graph max/mean pool -> xc[:, 0:256] ----------------
__global__ __launch_bounds__(512) void pool_kernel(const float* __restrict__ x4, float* __restrict__ xc) {
    int g = blockIdx.x;
    int h = threadIdx.x & 127;
    int part = threadIdx.x >> 7;        // 0..3 (100 nodes each)
    const float* base = x4 + ((long)g * NPG + part * 100) * H + h;
    float mx = -INFINITY, sm = 0.f;
#pragma unroll 4
    for (int i = 0; i < 100; ++i) {
        float v = base[(long)i * H];
        mx = fmaxf(mx, v);
        sm += v;
    }
    __shared__ float smx[4][128], ssm[4][128];
    smx[part][h] = mx; ssm[part][h] = sm;
    __syncthreads();
    if (part == 0) {
        float m = fmaxf(fmaxf(smx[0][h], smx[1][h]), fmaxf(smx[2][h], smx[3][h]));
        float s = ssm[0][h] + ssm[1][h] + ssm[2][h] + ssm[3][h];
        xc[(long)g * DHEAD + h] = m;
        xc[(long)g * DHEAD + H + h] = s * (1.f / NPG);
    }
}

// ---------------- conv1d(84->128,k=3) + relu + avgpool5 -> xs[t][b][o] ----------------
__global__ __launch_bounds__(128) void conv1d_pool(const float* __restrict__ in,
                                                   const float* __restrict__ WcT,
                                                   const float* __restrict__ bc,
                                                   float* __restrict__ xs) {
    int p = blockIdx.x;    // 0..18
    int b = blockIdx.y;    // 0..255
    int o = threadIdx.x;   // 0..127
    __shared__ float sIn[C_IN][8];
    const float* ib = in + (long)b * C_IN * LSEQ;
    for (int idx = threadIdx.x; idx < C_IN * 7; idx += 128) {
        int c = idx / 7, j = idx % 7;
        sIn[c][j] = ib[c * LSEQ + 5 * p + j];
    }
    __syncthreads();
    float a0 = 0, a1 = 0, a2 = 0, a3 = 0, a4 = 0;
    for (int c = 0; c < C_IN; ++c) {
        float i0 = sIn[c][0], i1 = sIn[c][1], i2 = sIn[c][2], i3 = sIn[c][3];
        float i4 = sIn[c][4], i5 = sIn[c][5], i6 = sIn[c][6];
        float w0 = WcT[(c * 3 + 0) * H + o];
        float w1 = WcT[(c * 3 + 1) * H + o];
        float w2 = WcT[(c * 3 + 2) * H + o];
        a0 += w0 * i0 + w1 * i1 + w2 * i2;
        a1 += w0 * i1 + w1 * i2 + w2 * i3;
        a2 += w0 * i2 + w1 * i3 + w2 * i4;
        a3 += w0 * i3 + w1 * i4 + w2 * i5;
        a4 += w0 * i4 + w1 * i5 + w2 * i6;
    }
    float bcv = bc[o];
    float r = fmaxf(a0 + bcv, 0.f) + fmaxf(a1 + bcv, 0.f) + fmaxf(a2 + bcv, 0.f)
            + fmaxf(a3 + bcv, 0.f) + fmaxf(a4 + bcv, 0.f);
    xs[((long)p * BGR + b) * H + o] = r * 0.2f;
}

// ---------------- gi = xs @ WihT + bih  (16 rows/block) ----------------
__global__ __launch_bounds__(384) void gi_gemm(const float* __restrict__ xs,
                                               const float* __restrict__ WihT,
                                               const float* __restrict__ bih,
                                               float* __restrict__ gi) {
    const long r0 = (long)blockIdx.x * 16;
    const int g = threadIdx.x;
    __shared__ __align__(16) float sX[16][H];
    for (int idx = threadIdx.x; idx < 16 * H; idx += 384)
        sX[idx >> 7][idx & (H - 1)] = xs[r0 * H + idx];
    __syncthreads();
    if (g >= G3) return;
    const float bv = bih[g];
    float acc[16];
#pragma unroll
    for (int r = 0; r < 16; ++r) acc[r] = bv;
    for (int k = 0; k < H; k += 4) {
        float w0 = WihT[(k + 0) * G3 + g], w1 = WihT[(k + 1) * G3 + g];
        float w2 = WihT[(k + 2) * G3 + g], w3 = WihT[(k + 3) * G3 + g];
#pragma unroll
        for (int r = 0; r < 16; ++r) {
            float4 xv = *(const float4*)&sX[r][k];
            acc[r] += xv.x * w0 + xv.y * w1 + xv.z * w2 + xv.w * w3;
        }
    }
#pragma unroll
    for (int r = 0; r < 16; ++r)
        gi[(r0 + r) * G3 + g] = acc[r];
}

// ---------------- full BiGRU recurrence ----------------
__device__ __forceinline__ float sigmoidf_(float x) { return 1.f / (1.f + expf(-x)); }

__global__ __launch_bounds__(384) void gru_kernel(
        const float* __restrict__ giF, const float* __restrict__ giB,
        const float* __restrict__ WhhTF, const float* __restrict__ WhhTB,
        const float* __restrict__ bhhF, const float* __restrict__ bhhB,
        float* __restrict__ xc) {
    const int b = blockIdx.x & (BGR - 1);
    const int dir = blockIdx.x >> 8;
    const float* gi   = dir ? giB : giF;
    const float* WhhT = dir ? WhhTB : WhhTF;
    const float* bhh  = dir ? bhhB : bhhF;
    const int g = threadIdx.x;
    const int gc = g < G3 ? g : (G3 - 1);

    float w[GH];
#pragma unroll
    for (int k = 0; k < GH; ++k) w[k] = WhhT[(long)k * G3 + gc];
    const float bh = bhh[gc];

    __shared__ __align__(16) float sh[GH];
    __shared__ float sgh[G3];
    if (g < GH) sh[g] = 0.f;
    __syncthreads();

    for (int tt = 0; tt < TT; ++tt) {
        const int t = dir ? (TT - 1 - tt) : tt;
        float acc = bh;
#pragma unroll
        for (int k4 = 0; k4 < GH / 4; ++k4) {
            float4 hv = *(const float4*)&sh[k4 * 4];
            acc += hv.x * w[k4 * 4] + hv.y * w[k4 * 4 + 1]
                 + hv.z * w[k4 * 4 + 2] + hv.w * w[k4 * 4 + 3];
        }
        if (g < G3) sgh[g] = acc;
        __syncthreads();
        if (g < GH) {
            const float* gib = gi + ((long)t * BGR + b) * G3;
            float r = sigmoidf_(gib[g] + sgh[g]);
            float z = sigmoidf_(gib[GH + g] + sgh[GH + g]);
            float n = tanhf(gib[2 * GH + g] + r * sgh[2 * GH + g]);
            float h2 = (1.f - z) * n + z * sh[g];
            sh[g] = h2;
            xc[(long)b * DHEAD + 256 + t * 240 + dir * GH + g] = h2;
        }
        __syncthreads();
    }
}

// ---------------- dense head: wave = 4 j x 8 b tile ----------------
__global__ __launch_bounds__(256) void dense1(const float* __restrict__ xc,
                                              const float* __restrict__ Wd1T,
                                              const float* __restrict__ bd1,
                                              float* __restrict__ d1) {
    const int wid  = blockIdx.x * 4 + (threadIdx.x >> 6);   // 0 .. 26*32-1
    const int lane = threadIdx.x & 63;
    const int jg = wid % 26;    // 26 groups of 4 j (104 >= 102)
    const int bg = wid / 26;    // 32 groups of 8 b
    const int j0 = jg * 4, b0 = bg * 8;

    float acc[4][8];
#pragma unroll
    for (int jj = 0; jj < 4; ++jj)
#pragma unroll
        for (int bb = 0; bb < 8; ++bb) acc[jj][bb] = 0.f;

    for (int i = lane; i < DHEAD / 4; i += 64) {
        float4 wv[4], xv[8];
#pragma unroll
        for (int jj = 0; jj < 4; ++jj) {
            int j = j0 + jj; if (j > D1O - 1) j = D1O - 1;
            wv[jj] = *(const float4*)(Wd1T + (long)j * DHEAD + i * 4);
        }
#pragma unroll
        for (int bb = 0; bb < 8; ++bb)
            xv[bb] = *(const float4*)(xc + (long)(b0 + bb) * DHEAD + i * 4);
#pragma unroll
        for (int jj = 0; jj < 4; ++jj)
#pragma unroll
            for (int bb = 0; bb < 8; ++bb)
                acc[jj][bb] += wv[jj].x * xv[bb].x + wv[jj].y * xv[bb].y
                             + wv[jj].z * xv[bb].z + wv[jj].w * xv[bb].w;
    }
#pragma unroll
    for (int m = 32; m >= 1; m >>= 1)
#pragma unroll
        for (int jj = 0; jj < 4; ++jj)
#pragma unroll
            for (int bb = 0; bb < 8; ++bb)
                acc[jj][bb] += __shfl_xor(acc[jj][bb], m, 64);
    if (lane < 32) {
        const int jj = lane >> 3, bb = lane & 7;
        const int j = j0 + jj;
        if (j < D1O)
            d1[(long)(b0 + bb) * D1O + j] = fmaxf(acc[jj][bb] + bd1[j], 0.f);
    }
}

__global__ void final_head(const float* __restrict__ d1, const float* __restrict__ Wd3,
                           const float* __restrict__ bd3, float* __restrict__ out) {
    int b = threadIdx.x;   // 256 threads, 1 block
    if (b >= BGR) return;
    float v0 = bd3[0], v1 = bd3[1];
    for (int k = 0; k < D1O; ++k) {
        float xv = d1[(long)b * D1O + k];
        v0 += xv * Wd3[k * 2 + 0];
        v1 += xv * Wd3[k * 2 + 1];
    }
    float m = fmaxf(v0, v1);
    float lse = m + logf(expf(v0 - m) + expf(v1 - m));
    out[b * 2 + 0] = v0 - lse;
    out[b * 2 + 1] = v1 - lse;
}

// ---------------- launch ----------------
extern "C" void kernel_launch(void* const* d_in, const int* in_sizes, int n_in,
                              void* d_out, int out_size, void* d_ws, size_t ws_size,
                              hipStream_t stream) {
    const float* x      = (const float*)d_in[0];
    const int*   ei     = (const int*)d_in[1];
    const float* tgt    = (const float*)d_in[3];
    const float* W1rel  = (const float*)d_in[4];
    const float* W1root = (const float*)d_in[5];
    const float* b1     = (const float*)d_in[6];
    const float* W2rel  = (const float*)d_in[7];
    const float* W2root = (const float*)d_in[8];
    const float* b2     = (const float*)d_in[9];
    const float* W3rel  = (const float*)d_in[10];
    const float* W3root = (const float*)d_in[11];
    const float* b3     = (const float*)d_in[12];
    const float* Wc     = (const float*)d_in[13];
    const float* bc     = (const float*)d_in[14];
    const float* Wih_f  = (const float*)d_in[15];
    const float* Whh_f  = (const float*)d_in[16];
    const float* bih_f  = (const float*)d_in[17];
    const float* bhh_f  = (const float*)d_in[18];
    const float* Wih_b  = (const float*)d_in[19];
    const float* Whh_b  = (const float*)d_in[20];
    const float* bih_b  = (const float*)d_in[21];
    const float* bhh_b  = (const float*)d_in[22];
    const float* Wd1    = (const float*)d_in[23];
    const float* bd1    = (const float*)d_in[24];
    const float* Wd3    = (const float*)d_in[25];
    const float* bd3    = (const float*)d_in[26];

    const int* srcI = ei;
    const int* dstI = ei + N_EDGES;

    // workspace layout (floats)
    float* ws = (float*)d_ws;
    size_t off = 0;
    float* AGG4  = ws + off; off += (size_t)N_NODES * 4;
    float* X1    = ws + off; off += (size_t)N_NODES * H;   // fp32: residual src, conv4 out
    float* XS    = ws + off; off += (size_t)TT * BGR * H;
    float* GIF   = ws + off; off += (size_t)TT * BGR * G3;
    float* GIB   = ws + off; off += (size_t)TT * BGR * G3;
    float* XC    = ws + off; off += (size_t)BGR * DHEAD;
    float* D1    = ws + off; off += (size_t)BGR * D1O + 2;
    float* WCT   = ws + off; off += (size_t)C_IN * 3 * H;
    float* WIHTF = ws + off; off += (size_t)H * G3;
    float* WIHTB = ws + off; off += (size_t)H * G3;
    float* WHHTF = ws + off; off += (size_t)GH * G3;
    float* WHHTB = ws + off; off += (size_t)GH * G3;
    float* WD1T  = ws + off; off += (size_t)DHEAD * D1O;
    off = (off + 3) & ~(size_t)3;                       // 16B align
    short* WBT2  = (short*)(ws + off); off += (size_t)H * KCOMB / 2;   // bf16 [128][256]
    short* WBT3  = (short*)(ws + off); off += (size_t)H * KCOMB / 2;
    short* AGGB  = (short*)(ws + off); off += (size_t)N_NODES * H / 2; // bf16 agg
    short* X1B   = (short*)(ws + off); off += (size_t)N_NODES * H / 2; // bf16 x1
    short* X2B   = (short*)(ws + off); off += (size_t)N_NODES * H / 2; // bf16 x2
    short* X3B   = (short*)(ws + off); off += (size_t)N_NODES * H / 2; // bf16 x3
    // int region
    int* ibase   = (int*)(ws + off);
    int* CNT     = ibase;                     // N
    int* CSR     = ibase + N_NODES;           // N * CAP

    // weight prep
    prep_fused<<<PREP_BLOCKS, 256, 0, stream>>>(Wc, WCT, Wih_f, WIHTF, Wih_b, WIHTB,
                                                Whh_f, WHHTF, Whh_b, WHHTB,
                                                W2rel, W2root, WBT2, W3rel, W3root, WBT3);
    transpose_tiled<<<dim3((DHEAD + 31) / 32, (D1O + 31) / 32), 256, 0, stream>>>(Wd1, WD1T, DHEAD, D1O);

    // ---- XCD-partitioned CSR build ----
    hipMemsetAsync(CNT, 0, (size_t)N_NODES * sizeof(int), stream);
    xcd_scatter<<<NXCD * SGRP, 256, 0, stream>>>(srcI, dstI, CNT, CSR, N_EDGES);

    // conv1: x (N,4) -> x1 (N,128) fp32 + bf16 copy
    agg4_csr<<<(N_NODES * 4) / 256, 256, 0, stream>>>(CNT, CSR, x, AGG4);
    gc1_transform<<<(N_NODES * H) / 256, 256, 0, stream>>>(AGG4, x, W1rel, W1root, b1, X1, X1B);

    // conv2: x1 -> x2 (bf16 only)
    agg128_bf<<<N_NODES / 16, 256, 0, stream>>>(CNT, CSR, X1B, AGGB);
    gc_mfma<0, 0, 1><<<N_NODES / 128, 256, 0, stream>>>(AGGB, X1B, WBT2, b2, nullptr, nullptr, X2B);

    // conv3: x2 -> x3 (bf16 only), + residual x1 (fp32)
    agg128_bf<<<N_NODES / 16, 256, 0, stream>>>(CNT, CSR, X2B, AGGB);
    gc_mfma<1, 0, 1><<<N_NODES / 128, 256, 0, stream>>>(AGGB, X2B, WBT3, b3, X1, nullptr, X3B);

    // conv4: x3 -> x4 (fp32, reuses X1; residual read of X1 finished in conv3)
    agg128_bf<<<N_NODES / 16, 256, 0, stream>>>(CNT, CSR, X3B, AGGB);
    gc_mfma<0, 1, 0><<<N_NODES / 128, 256, 0, stream>>>(AGGB, X3B, WBT3, b3, nullptr, X1, nullptr);

    // pooling -> xc[:, 0:256]
    pool_kernel<<<BGR, 512, 0, stream>>>(X1, XC);

    // conv1d + relu + avgpool -> xs
    conv1d_pool<<<dim3(TT, BGR), 128, 0, stream>>>(tgt, WCT, bc, XS);

    // gi GEMMs (16 rows/block)
    gi_gemm<<<(TT * BGR) / 16, 384, 0, stream>>>(XS, WIHTF, bih_f, GIF);
    gi_gemm<<<(TT * BGR) / 16, 384, 0, stream>>>(XS, WIHTB, bih_b, GIB);

    // BiGRU -> xc[:, 256:4816]
    gru_kernel<<<2 * BGR, 384, 0, stream>>>(GIF, GIB, WHHTF, WHHTB, bhh_f, bhh_b, XC);

    // dense head
    dense1<<<(26 * 32) / 4, 256, 0, stream>>>(XC, WD1T, bd1, D1);
    final_head<<<1, 256, 0, stream>>>(D1, Wd3, bd3, (float*)d_out);
}

// Round 14
// 679.310 us; speedup vs baseline: 1.2058x; 1.0445x over previous
//
#include <hip/hip_runtime.h>
#include <cmath>

// Problem constants (match reference setup_inputs)
constexpr int N_NODES = 102400;
constexpr int N_EDGES = 1600000;
constexpr int BGR     = 256;     // graphs
constexpr int NPG     = 400;     // nodes per graph
constexpr int F_IN    = 4;
constexpr int H       = 128;
constexpr int GH      = 120;
constexpr int G3      = 360;     // 3*GH
constexpr int C_IN    = 84;
constexpr int LSEQ    = 100;
constexpr int TT      = 19;      // GRU timesteps
constexpr int DHEAD   = 4816;    // 256 + 19*240
constexpr int D1O     = 102;
constexpr int KCOMB   = 256;     // combined K for fused [agg|xin] GEMM
constexpr int CAP     = 64;      // bucket capacity per node
constexpr int NXCD    = 8;
constexpr int NPX     = N_NODES / NXCD;   // 12800 nodes per XCD partition (scatter)
constexpr int SGRP    = 104;              // blocks per XCD group for xcd_scatter

using short8 = __attribute__((ext_vector_type(8))) short;
using f32x4  = __attribute__((ext_vector_type(4))) float;

__device__ __forceinline__ short f2bf(float f) {      // RNE float->bf16 bits
    unsigned u = __float_as_uint(f);
    u += 0x7FFFu + ((u >> 16) & 1u);
    return (short)(u >> 16);
}
__device__ __forceinline__ float bf2f(short s) {
    return __uint_as_float(((unsigned)(unsigned short)s) << 16);
}

// ---------------- fused small weight prep (5 transposes + 2 bf16 precasts) ----------------
__device__ __forceinline__ void tr_seg(const float* __restrict__ in, float* __restrict__ out,
                                       int R, int C, int i) {
    if (i < R * C) {
        int r = i / C, c = i % C;
        out[(long)c * R + r] = in[i];
    }
}
__device__ __forceinline__ void wbt_seg(const float* __restrict__ Wrel, const float* __restrict__ Wroot,
                                        short* __restrict__ WBT, int i) {
    if (i < H * KCOMB) {
        int h = i >> 8, k = i & 255;
        float v = (k < H) ? Wrel[k * H + h] : Wroot[(k - H) * H + h];
        WBT[h * KCOMB + k] = f2bf(v);
    }
}
constexpr int PB0 = 126;   // Wc   (128,252)T
constexpr int PB1 = 180;   // Wihf (360,128)T
constexpr int PB2 = 180;   // Wihb
constexpr int PB3 = 169;   // Whhf (360,120)T
constexpr int PB4 = 169;   // Whhb
constexpr int PB6 = 128;   // WBT2
constexpr int PB7 = 128;   // WBT3
constexpr int PREP_BLOCKS = PB0+PB1+PB2+PB3+PB4+PB6+PB7;

__global__ void prep_fused(const float* Wc, float* WCT,
                           const float* Wihf, float* WIHTF,
                           const float* Wihb, float* WIHTB,
                           const float* Whhf, float* WHHTF,
                           const float* Whhb, float* WHHTB,
                           const float* W2rel, const float* W2root, short* WBT2,
                           const float* W3rel, const float* W3root, short* WBT3) {
    int b = blockIdx.x;
    int t = threadIdx.x;
    if (b < PB0) { tr_seg(Wc,   WCT,   128, 252, b * 256 + t); return; }  b -= PB0;
    if (b < PB1) { tr_seg(Wihf, WIHTF, G3,  H,   b * 256 + t); return; }  b -= PB1;
    if (b < PB2) { tr_seg(Wihb, WIHTB, G3,  H,   b * 256 + t); return; }  b -= PB2;
    if (b < PB3) { tr_seg(Whhf, WHHTF, G3,  GH,  b * 256 + t); return; }  b -= PB3;
    if (b < PB4) { tr_seg(Whhb, WHHTB, G3,  GH,  b * 256 + t); return; }  b -= PB4;
    if (b < PB6) { wbt_seg(W2rel, W2root, WBT2, b * 256 + t); return; }   b -= PB6;
    wbt_seg(W3rel, W3root, WBT3, b * 256 + t);
}

// ---------------- LDS-tiled transpose for Wd1 (4816,102) -> (102,4816) ----------------
__global__ __launch_bounds__(256) void transpose_tiled(const float* __restrict__ in,
                                                       float* __restrict__ out, int R, int C) {
    __shared__ float tile[32][33];
    const int rb = blockIdx.x * 32, cb = blockIdx.y * 32;
    const int tx = threadIdx.x & 31, ty = threadIdx.x >> 5;   // 32 x 8
#pragma unroll
    for (int yy = 0; yy < 32; yy += 8) {
        int r = rb + ty + yy, c = cb + tx;
        if (r < R && c < C) tile[ty + yy][tx] = in[(long)r * C + c];
    }
    __syncthreads();
#pragma unroll
    for (int yy = 0; yy < 32; yy += 8) {
        int ro = cb + ty + yy, co = rb + tx;
        if (ro < C && co < R) out[(long)ro * R + co] = tile[tx][ty + yy];
    }
}

// ================= FUSED: xcd_scatter [0,832) + conv1d_pool [832,832+2432) =================
constexpr int SCB = NXCD * SGRP;            // 832 scatter blocks (keeps blockIdx&7 pattern)
constexpr int C1B = (TT * BGR) / 2;         // 2432 conv1d blocks (2 (p,b) pairs each)

__global__ __launch_bounds__(256) void scatter_conv1d(
        const int* __restrict__ src, const int* __restrict__ dst,
        int* __restrict__ cnt, int* __restrict__ csr, int E,
        const float* __restrict__ tin, const float* __restrict__ WcT,
        const float* __restrict__ bc, float* __restrict__ xs) {
    if (blockIdx.x < SCB) {
        // ---- XCD-partitioned scatter (r10-verified) ----
        const int g   = blockIdx.x & (NXCD - 1);
        const int grp = blockIdx.x >> 3;
        const int nlo = g * NPX, nhi = nlo + NPX;
        const int stride = SGRP * 256 * 4;
        for (int e = (grp * 256 + threadIdx.x) * 4; e + 3 < E; e += stride) {
            const int4 s = *(const int4*)(src + e);
            const int4 d = *(const int4*)(dst + e);
            if (d.x >= nlo && d.x < nhi) { int p = atomicAdd(&cnt[d.x], 1); csr[((long)d.x << 6) + p] = s.x; }
            if (d.y >= nlo && d.y < nhi) { int p = atomicAdd(&cnt[d.y], 1); csr[((long)d.y << 6) + p] = s.y; }
            if (d.z >= nlo && d.z < nhi) { int p = atomicAdd(&cnt[d.z], 1); csr[((long)d.z << 6) + p] = s.z; }
            if (d.w >= nlo && d.w < nhi) { int p = atomicAdd(&cnt[d.w], 1); csr[((long)d.w << 6) + p] = s.w; }
        }
        return;
    }
    // ---- conv1d(84->128,k=3)+relu+avgpool5, 2 (p,b) pairs per block ----
    __shared__ float sIn[2][C_IN][8];
    const int half = threadIdx.x >> 7;      // 0..1
    const int o    = threadIdx.x & 127;
    const int id   = (blockIdx.x - SCB) * 2 + half;   // 0..4863
    const int p = id / BGR, b = id % BGR;
    const float* ib = tin + (long)b * C_IN * LSEQ;
    for (int idx = o; idx < C_IN * 7; idx += 128) {
        int c = idx / 7, j = idx % 7;
        sIn[half][c][j] = ib[c * LSEQ + 5 * p + j];
    }
    __syncthreads();
    float a0 = 0, a1 = 0, a2 = 0, a3 = 0, a4 = 0;
    for (int c = 0; c < C_IN; ++c) {
        float i0 = sIn[half][c][0], i1 = sIn[half][c][1], i2 = sIn[half][c][2], i3 = sIn[half][c][3];
        float i4 = sIn[half][c][4], i5 = sIn[half][c][5], i6 = sIn[half][c][6];
        float w0 = WcT[(c * 3 + 0) * H + o];
        float w1 = WcT[(c * 3 + 1) * H + o];
        float w2 = WcT[(c * 3 + 2) * H + o];
        a0 += w0 * i0 + w1 * i1 + w2 * i2;
        a1 += w0 * i1 + w1 * i2 + w2 * i3;
        a2 += w0 * i2 + w1 * i3 + w2 * i4;
        a3 += w0 * i3 + w1 * i4 + w2 * i5;
        a4 += w0 * i4 + w1 * i5 + w2 * i6;
    }
    float bcv = bc[o];
    float r = fmaxf(a0 + bcv, 0.f) + fmaxf(a1 + bcv, 0.f) + fmaxf(a2 + bcv, 0.f)
            + fmaxf(a3 + bcv, 0.f) + fmaxf(a4 + bcv, 0.f);
    xs[((long)p * BGR + b) * H + o] = r * 0.2f;
}

// ================= FUSED: agg4_csr + gi_gemm(F) + gi_gemm(B), 384 threads =================
constexpr int A4B = (N_NODES * 4 + 383) / 384;   // 1067
constexpr int GIB_ = (TT * BGR) / 16;            // 304 per direction

__device__ __forceinline__ void gi_body(const float* __restrict__ xs,
                                        const float* __restrict__ WihT,
                                        const float* __restrict__ bih,
                                        float* __restrict__ gi, int bid) {
    const long r0 = (long)bid * 16;
    const int g = threadIdx.x;
    __shared__ __align__(16) float sX[16][H];
    for (int idx = threadIdx.x; idx < 16 * H; idx += 384)
        sX[idx >> 7][idx & (H - 1)] = xs[r0 * H + idx];
    __syncthreads();
    if (g >= G3) return;
    const float bv = bih[g];
    float acc[16];
#pragma unroll
    for (int r = 0; r < 16; ++r) acc[r] = bv;
    for (int k = 0; k < H; k += 4) {
        float w0 = WihT[(k + 0) * G3 + g], w1 = WihT[(k + 1) * G3 + g];
        float w2 = WihT[(k + 2) * G3 + g], w3 = WihT[(k + 3) * G3 + g];
#pragma unroll
        for (int r = 0; r < 16; ++r) {
            float4 xv = *(const float4*)&sX[r][k];
            acc[r] += xv.x * w0 + xv.y * w1 + xv.z * w2 + xv.w * w3;
        }
    }
#pragma unroll
    for (int r = 0; r < 16; ++r)
        gi[(r0 + r) * G3 + g] = acc[r];
}

__global__ __launch_bounds__(384) void agg4_gi(
        const int* __restrict__ cnt, const int* __restrict__ csr,
        const float* __restrict__ x, float* __restrict__ agg,
        const float* __restrict__ xs,
        const float* __restrict__ WihTF, const float* __restrict__ bihF, float* __restrict__ giF,
        const float* __restrict__ WihTB, const float* __restrict__ bihB, float* __restrict__ giB) {
    int b = blockIdx.x;
    if (b < A4B) {
        int i = b * 384 + threadIdx.x;
        if (i < N_NODES * 4) {
            int n = i >> 2, c = i & 3;
            const int cn = cnt[n];
            const int* idx = csr + ((long)n << 6);
            float acc = 0.f;
            for (int j = 0; j < cn; ++j) acc += x[(long)idx[j] * 4 + c];
            agg[i] = acc;
        }
        return;
    }
    b -= A4B;
    if (b < GIB_) { gi_body(xs, WihTF, bihF, giF, b); return; }
    b -= GIB_;
    gi_body(xs, WihTB, bihB, giB, b);
}

// ================= conv1 transform: fp32 out + bf16 copy =================
__global__ void gc1_transform(const float* __restrict__ agg4, const float* __restrict__ x,
                              const float* __restrict__ Wrel, const float* __restrict__ Wroot,
                              const float* __restrict__ bias, float* __restrict__ out,
                              short* __restrict__ outb) {
    long i = (long)blockIdx.x * 256 + threadIdx.x;   // over N*H
    int h = (int)(i & (H - 1));
    long n = i >> 7;
    const float4 a  = *(const float4*)(agg4 + n * 4);
    const float4 xv = *(const float4*)(x    + n * 4);
    float acc = bias[h]
        + a.x  * Wrel[0 * H + h] + a.y  * Wrel[1 * H + h]
        + a.z  * Wrel[2 * H + h] + a.w  * Wrel[3 * H + h]
        + xv.x * Wroot[0 * H + h] + xv.y * Wroot[1 * H + h]
        + xv.z * Wroot[2 * H + h] + xv.w * Wroot[3 * H + h];
    float v = fmaxf(acc, 0.f);
    out[i] = v;
    outb[i] = f2bf(v);
}

// ================= bf16 CSR gather body (r13-verified, 8-deep unroll) =================
__device__ __forceinline__ void agg_body(const int* __restrict__ cnt,
                                         const int* __restrict__ csr,
                                         const short* __restrict__ xb,
                                         short* __restrict__ aggb, int n, int lane) {
    const int cn = cnt[n];
    const int* idx = csr + ((long)n << 6);
    const short* xs = xb + lane * 8;
    float acc[8];
#pragma unroll
    for (int q = 0; q < 8; ++q) acc[q] = 0.f;
    int j = 0;
    for (; j + 7 < cn; j += 8) {
        const int4 i0 = *(const int4*)(idx + j);
        const int4 i1 = *(const int4*)(idx + j + 4);
        const short8 r0 = *(const short8*)(xs + (long)i0.x * H);
        const short8 r1 = *(const short8*)(xs + (long)i0.y * H);
        const short8 r2 = *(const short8*)(xs + (long)i0.z * H);
        const short8 r3 = *(const short8*)(xs + (long)i0.w * H);
        const short8 r4 = *(const short8*)(xs + (long)i1.x * H);
        const short8 r5 = *(const short8*)(xs + (long)i1.y * H);
        const short8 r6 = *(const short8*)(xs + (long)i1.z * H);
        const short8 r7 = *(const short8*)(xs + (long)i1.w * H);
#pragma unroll
        for (int q = 0; q < 8; ++q)
            acc[q] += ((bf2f(r0[q]) + bf2f(r1[q])) + (bf2f(r2[q]) + bf2f(r3[q])))
                    + ((bf2f(r4[q]) + bf2f(r5[q])) + (bf2f(r6[q]) + bf2f(r7[q])));
    }
    for (; j + 3 < cn; j += 4) {
        const int4 ii = *(const int4*)(idx + j);
        const short8 r0 = *(const short8*)(xs + (long)ii.x * H);
        const short8 r1 = *(const short8*)(xs + (long)ii.y * H);
        const short8 r2 = *(const short8*)(xs + (long)ii.z * H);
        const short8 r3 = *(const short8*)(xs + (long)ii.w * H);
#pragma unroll
        for (int q = 0; q < 8; ++q)
            acc[q] += (bf2f(r0[q]) + bf2f(r1[q])) + (bf2f(r2[q]) + bf2f(r3[q]));
    }
    for (; j < cn; ++j) {
        const short8 r0 = *(const short8*)(xs + (long)idx[j] * H);
#pragma unroll
        for (int q = 0; q < 8; ++q) acc[q] += bf2f(r0[q]);
    }
    short8 o;
#pragma unroll
    for (int q = 0; q < 8; ++q) o[q] = f2bf(acc[q]);
    *(short8*)(aggb + (long)n * H + lane * 8) = o;
}

// standalone gather (convs 3,4): 16 nodes per 256-thread block
__global__ __launch_bounds__(256) void agg128_bf(const int* __restrict__ cnt,
                                                 const int* __restrict__ csr,
                                                 const short* __restrict__ xb,
                                                 short* __restrict__ aggb) {
    agg_body(cnt, csr, xb, aggb, blockIdx.x * 16 + (threadIdx.x >> 4), threadIdx.x & 15);
}

// ================= FUSED: agg128_bf(conv2) + gru_kernel, 384 threads =================
constexpr int AGB = (N_NODES + 23) / 24;   // 4267 gather blocks (24 nodes each)

__device__ __forceinline__ float sigmoidf_(float x) { return 1.f / (1.f + expf(-x)); }

__device__ void gru_body(const float* __restrict__ gi, const float* __restrict__ WhhT,
                         const float* __restrict__ bhh, float* __restrict__ xc,
                         int b, int dir) {
    const int g = threadIdx.x;
    const int gc = g < G3 ? g : (G3 - 1);
    float w[GH];
#pragma unroll
    for (int k = 0; k < GH; ++k) w[k] = WhhT[(long)k * G3 + gc];
    const float bh = bhh[gc];

    __shared__ __align__(16) float sh[GH];
    __shared__ float sgh[G3];
    if (g < GH) sh[g] = 0.f;
    __syncthreads();

    for (int tt = 0; tt < TT; ++tt) {
        const int t = dir ? (TT - 1 - tt) : tt;
        float acc = bh;
#pragma unroll
        for (int k4 = 0; k4 < GH / 4; ++k4) {
            float4 hv = *(const float4*)&sh[k4 * 4];
            acc += hv.x * w[k4 * 4] + hv.y * w[k4 * 4 + 1]
                 + hv.z * w[k4 * 4 + 2] + hv.w * w[k4 * 4 + 3];
        }
        if (g < G3) sgh[g] = acc;
        __syncthreads();
        if (g < GH) {
            const float* gib = gi + ((long)t * BGR + b) * G3;
            float r = sigmoidf_(gib[g] + sgh[g]);
            float z = sigmoidf_(gib[GH + g] + sgh[GH + g]);
            float n = tanhf(gib[2 * GH + g] + r * sgh[2 * GH + g]);
            float h2 = (1.f - z) * n + z * sh[g];
            sh[g] = h2;
            xc[(long)b * DHEAD + 256 + t * 240 + dir * GH + g] = h2;
        }
        __syncthreads();
    }
}

__global__ __launch_bounds__(384) void agg2_gru(
        const int* __restrict__ cnt, const int* __restrict__ csr,
        const short* __restrict__ xb, short* __restrict__ aggb,
        const float* __restrict__ giF, const float* __restrict__ giB,
        const float* __restrict__ WhhTF, const float* __restrict__ WhhTB,
        const float* __restrict__ bhhF, const float* __restrict__ bhhB,
        float* __restrict__ xc) {
    if (blockIdx.x < AGB) {
        const int n = blockIdx.x * 24 + (threadIdx.x >> 4);
        if (n < N_NODES) agg_body(cnt, csr, xb, aggb, n, threadIdx.x & 15);
        return;
    }
    const int bid = blockIdx.x - AGB;          // 0..511
    const int b = bid & (BGR - 1), dir = bid >> 8;
    gru_body(dir ? giB : giF, dir ? WhhTB : WhhTF, dir ? bhhB : bhhF, xc, b, dir);
}

// ---------------- GraphConv node transform via bf16 MFMA ----------------
template <int RES, int OUTF, int OUTB>
__global__ __launch_bounds__(256) void gc_mfma(
        const short* __restrict__ aggb, const short* __restrict__ xinb,
        const short* __restrict__ WBT, const float* __restrict__ bias,
        const float* __restrict__ res, float* __restrict__ outf,
        short* __restrict__ outb) {
    const int wid   = threadIdx.x >> 6;     // 0..3
    const int lane  = threadIdx.x & 63;
    const int l15   = lane & 15;
    const int kslot = lane >> 4;            // 0..3
    const long n0   = (long)blockIdx.x * 128 + wid * 32;

    f32x4 acc[2][8];
#pragma unroll
    for (int i = 0; i < 2; ++i)
#pragma unroll
        for (int j = 0; j < 8; ++j) acc[i][j] = (f32x4){0.f, 0.f, 0.f, 0.f};

#pragma unroll
    for (int ks = 0; ks < 8; ++ks) {        // combined-k step of 32
        const short* srcb = (ks < 4) ? aggb : xinb;
        const int koff = (ks < 4 ? ks * 32 : (ks - 4) * 32) + kslot * 8;
        short8 afr[2];
#pragma unroll
        for (int rt = 0; rt < 2; ++rt)
            afr[rt] = *(const short8*)(srcb + (n0 + rt * 16 + l15) * H + koff);
        const int kb = ks * 32 + kslot * 8;
        short8 bfr[8];
#pragma unroll
        for (int ct = 0; ct < 8; ++ct)
            bfr[ct] = *(const short8*)(WBT + (long)(ct * 16 + l15) * KCOMB + kb);
#pragma unroll
        for (int rt = 0; rt < 2; ++rt)
#pragma unroll
            for (int ct = 0; ct < 8; ++ct)
                acc[rt][ct] = __builtin_amdgcn_mfma_f32_16x16x32_bf16(
                    afr[rt], bfr[ct], acc[rt][ct], 0, 0, 0);
    }

#pragma unroll
    for (int rt = 0; rt < 2; ++rt) {
        const long rbase = n0 + rt * 16 + kslot * 4;
#pragma unroll
        for (int ct = 0; ct < 8; ++ct) {
            const int h = ct * 16 + l15;
            const float bv = bias[h];
#pragma unroll
            for (int r = 0; r < 4; ++r) {
                const long rowi = rbase + r;
                float v = fmaxf(acc[rt][ct][r] + bv, 0.f);
                if (RES) v += res[rowi * H + h];
                if (OUTF) outf[rowi * H + h] = v;
                if (OUTB) outb[rowi * H + h] = f2bf(v);
            }
        }
    }
}

// ---------------- graph max/mean pool -> xc[:, 0:256] ----------------
__global__ __launch_bounds__(512) void pool_kernel(const float* __restrict__ x4, float* __restrict__ xc) {
    int g = blockIdx.x;
    int h = threadIdx.x & 127;
    int part = threadIdx.x >> 7;        // 0..3 (100 nodes each)
    const float* base = x4 + ((long)g * NPG + part * 100) * H + h;
    float mx = -INFINITY, sm = 0.f;
#pragma unroll 4
    for (int i = 0; i < 100; ++i) {
        float v = base[(long)i * H];
        mx = fmaxf(mx, v);
        sm += v;
    }
    __shared__ float smx[4][128], ssm[4][128];
    smx[part][h] = mx; ssm[part][h] = sm;
    __syncthreads();
    if (part == 0) {
        float m = fmaxf(fmaxf(smx[0][h], smx[1][h]), fmaxf(smx[2][h], smx[3][h]));
        float s = ssm[0][h] + ssm[1][h] + ssm[2][h] + ssm[3][h];
        xc[(long)g * DHEAD + h] = m;
        xc[(long)g * DHEAD + H + h] = s * (1.f / NPG);
    }
}

// ---------------- dense head: 2-way k-split, atomic partials into zeroed D1 ----------------
__global__ __launch_bounds__(256) void dense1(const float* __restrict__ xc,
                                              const float* __restrict__ Wd1T,
                                              float* __restrict__ d1) {
    const int wid0 = blockIdx.x * 4 + (threadIdx.x >> 6);   // 0 .. 26*32*2-1
    const int lane = threadIdx.x & 63;
    const int ks   = wid0 & 1;              // k-split half
    const int wid  = wid0 >> 1;
    const int jg = wid % 26;
    const int bg = wid / 26;
    const int j0 = jg * 4, b0 = bg * 8;
    const int i0 = ks * 602, i1 = i0 + 602;  // float4 index range (1204 total)

    float acc[4][8];
#pragma unroll
    for (int jj = 0; jj < 4; ++jj)
#pragma unroll
        for (int bb = 0; bb < 8; ++bb) acc[jj][bb] = 0.f;

    for (int i = i0 + lane; i < i1; i += 64) {
        float4 wv[4], xv[8];
#pragma unroll
        for (int jj = 0; jj < 4; ++jj) {
            int j = j0 + jj; if (j > D1O - 1) j = D1O - 1;
            wv[jj] = *(const float4*)(Wd1T + (long)j * DHEAD + i * 4);
        }
#pragma unroll
        for (int bb = 0; bb < 8; ++bb)
            xv[bb] = *(const float4*)(xc + (long)(b0 + bb) * DHEAD + i * 4);
#pragma unroll
        for (int jj = 0; jj < 4; ++jj)
#pragma unroll
            for (int bb = 0; bb < 8; ++bb)
                acc[jj][bb] += wv[jj].x * xv[bb].x + wv[jj].y * xv[bb].y
                             + wv[jj].z * xv[bb].z + wv[jj].w * xv[bb].w;
    }
#pragma unroll
    for (int m = 32; m >= 1; m >>= 1)
#pragma unroll
        for (int jj = 0; jj < 4; ++jj)
#pragma unroll
            for (int bb = 0; bb < 8; ++bb)
                acc[jj][bb] += __shfl_xor(acc[jj][bb], m, 64);
    if (lane < 32) {
        const int jj = lane >> 3, bb = lane & 7;
        const int j = j0 + jj;
        if (j < D1O)
            atomicAdd(&d1[(long)(b0 + bb) * D1O + j], acc[jj][bb]);
    }
}

// bias+relu folded here (d1 holds raw partial sums)
__global__ void final_head(const float* __restrict__ d1, const float* __restrict__ bd1,
                           const float* __restrict__ Wd3, const float* __restrict__ bd3,
                           float* __restrict__ out) {
    int b = threadIdx.x;   // 256 threads, 1 block
    if (b >= BGR) return;
    float v0 = bd3[0], v1 = bd3[1];
    for (int k = 0; k < D1O; ++k) {
        float xv = fmaxf(d1[(long)b * D1O + k] + bd1[k], 0.f);
        v0 += xv * Wd3[k * 2 + 0];
        v1 += xv * Wd3[k * 2 + 1];
    }
    float m = fmaxf(v0, v1);
    float lse = m + logf(expf(v0 - m) + expf(v1 - m));
    out[b * 2 + 0] = v0 - lse;
    out[b * 2 + 1] = v1 - lse;
}

// ---------------- launch ----------------
extern "C" void kernel_launch(void* const* d_in, const int* in_sizes, int n_in,
                              void* d_out, int out_size, void* d_ws, size_t ws_size,
                              hipStream_t stream) {
    const float* x      = (const float*)d_in[0];
    const int*   ei     = (const int*)d_in[1];
    const float* tgt    = (const float*)d_in[3];
    const float* W1rel  = (const float*)d_in[4];
    const float* W1root = (const float*)d_in[5];
    const float* b1     = (const float*)d_in[6];
    const float* W2rel  = (const float*)d_in[7];
    const float* W2root = (const float*)d_in[8];
    const float* b2     = (const float*)d_in[9];
    const float* W3rel  = (const float*)d_in[10];
    const float* W3root = (const float*)d_in[11];
    const float* b3     = (const float*)d_in[12];
    const float* Wc     = (const float*)d_in[13];
    const float* bc     = (const float*)d_in[14];
    const float* Wih_f  = (const float*)d_in[15];
    const float* Whh_f  = (const float*)d_in[16];
    const float* bih_f  = (const float*)d_in[17];
    const float* bhh_f  = (const float*)d_in[18];
    const float* Wih_b  = (const float*)d_in[19];
    const float* Whh_b  = (const float*)d_in[20];
    const float* bih_b  = (const float*)d_in[21];
    const float* bhh_b  = (const float*)d_in[22];
    const float* Wd1    = (const float*)d_in[23];
    const float* bd1    = (const float*)d_in[24];
    const float* Wd3    = (const float*)d_in[25];
    const float* bd3    = (const float*)d_in[26];

    const int* srcI = ei;
    const int* dstI = ei + N_EDGES;

    // workspace layout (floats)
    float* ws = (float*)d_ws;
    size_t off = 0;
    float* AGG4  = ws + off; off += (size_t)N_NODES * 4;
    float* X1    = ws + off; off += (size_t)N_NODES * H;   // fp32: residual src, conv4 out
    float* XS    = ws + off; off += (size_t)TT * BGR * H;
    float* GIF   = ws + off; off += (size_t)TT * BGR * G3;
    float* GIB   = ws + off; off += (size_t)TT * BGR * G3;
    float* XC    = ws + off; off += (size_t)BGR * DHEAD;
    float* D1    = ws + off; off += (size_t)BGR * D1O + 2;
    float* WCT   = ws + off; off += (size_t)C_IN * 3 * H;
    float* WIHTF = ws + off; off += (size_t)H * G3;
    float* WIHTB = ws + off; off += (size_t)H * G3;
    float* WHHTF = ws + off; off += (size_t)GH * G3;
    float* WHHTB = ws + off; off += (size_t)GH * G3;
    float* WD1T  = ws + off; off += (size_t)DHEAD * D1O;
    off = (off + 3) & ~(size_t)3;                       // 16B align
    short* WBT2  = (short*)(ws + off); off += (size_t)H * KCOMB / 2;   // bf16 [128][256]
    short* WBT3  = (short*)(ws + off); off += (size_t)H * KCOMB / 2;
    short* AGGB  = (short*)(ws + off); off += (size_t)N_NODES * H / 2; // bf16 agg
    short* X1B   = (short*)(ws + off); off += (size_t)N_NODES * H / 2; // bf16 x1
    short* X2B   = (short*)(ws + off); off += (size_t)N_NODES * H / 2; // bf16 x2
    short* X3B   = (short*)(ws + off); off += (size_t)N_NODES * H / 2; // bf16 x3
    // int region
    int* ibase   = (int*)(ws + off);
    int* CNT     = ibase;                     // N
    int* CSR     = ibase + N_NODES;           // N * CAP

    // weight prep
    prep_fused<<<PREP_BLOCKS, 256, 0, stream>>>(Wc, WCT, Wih_f, WIHTF, Wih_b, WIHTB,
                                                Whh_f, WHHTF, Whh_b, WHHTB,
                                                W2rel, W2root, WBT2, W3rel, W3root, WBT3);
    transpose_tiled<<<dim3((DHEAD + 31) / 32, (D1O + 31) / 32), 256, 0, stream>>>(Wd1, WD1T, DHEAD, D1O);

    // zero CNT + D1 (dense1 accumulates atomically)
    hipMemsetAsync(CNT, 0, (size_t)N_NODES * sizeof(int), stream);
    hipMemsetAsync(D1, 0, (size_t)BGR * D1O * sizeof(float), stream);

    // ---- FUSED: XCD scatter || conv1d+pool ----
    scatter_conv1d<<<SCB + C1B, 256, 0, stream>>>(srcI, dstI, CNT, CSR, N_EDGES,
                                                  tgt, WCT, bc, XS);

    // ---- FUSED: conv1 aggregation || gi GEMMs ----
    agg4_gi<<<A4B + 2 * GIB_, 384, 0, stream>>>(CNT, CSR, x, AGG4, XS,
                                                WIHTF, bih_f, GIF, WIHTB, bih_b, GIB);

    // conv1 transform: fp32 + bf16 copy
    gc1_transform<<<(N_NODES * H) / 256, 256, 0, stream>>>(AGG4, x, W1rel, W1root, b1, X1, X1B);

    // ---- FUSED: conv2 gather || BiGRU ----
    agg2_gru<<<AGB + 2 * BGR, 384, 0, stream>>>(CNT, CSR, X1B, AGGB, GIF, GIB,
                                                WHHTF, WHHTB, bhh_f, bhh_b, XC);
    gc_mfma<0, 0, 1><<<N_NODES / 128, 256, 0, stream>>>(AGGB, X1B, WBT2, b2, nullptr, nullptr, X2B);

    // conv3: x2 -> x3 (bf16 only), + residual x1 (fp32)
    agg128_bf<<<N_NODES / 16, 256, 0, stream>>>(CNT, CSR, X2B, AGGB);
    gc_mfma<1, 0, 1><<<N_NODES / 128, 256, 0, stream>>>(AGGB, X2B, WBT3, b3, X1, nullptr, X3B);

    // conv4: x3 -> x4 (fp32, reuses X1)
    agg128_bf<<<N_NODES / 16, 256, 0, stream>>>(CNT, CSR, X3B, AGGB);
    gc_mfma<0, 1, 0><<<N_NODES / 128, 256, 0, stream>>>(AGGB, X3B, WBT3, b3, nullptr, X1, nullptr);

    // pooling -> xc[:, 0:256]
    pool_kernel<<<BGR, 512, 0, stream>>>(X1, XC);

    // dense head (k-split atomic) + final
    dense1<<<(26 * 32 * 2) / 4, 256, 0, stream>>>(XC, WD1T, D1);
    final_head<<<1, 256, 0, stream>>>(D1, bd1, Wd3, bd3, (float*)d_out);
}

// Round 15
// 662.890 us; speedup vs baseline: 1.2356x; 1.0248x over previous
//
#include <hip/hip_runtime.h>
#include <cmath>

// Problem constants (match reference setup_inputs)
constexpr int N_NODES = 102400;
constexpr int N_EDGES = 1600000;
constexpr int BGR     = 256;     // graphs
constexpr int NPG     = 400;     // nodes per graph
constexpr int F_IN    = 4;
constexpr int H       = 128;
constexpr int GH      = 120;
constexpr int G3      = 360;     // 3*GH
constexpr int C_IN    = 84;
constexpr int LSEQ    = 100;
constexpr int TT      = 19;      // GRU timesteps
constexpr int DHEAD   = 4816;    // 256 + 19*240
constexpr int D1O     = 102;
constexpr int KCOMB   = 256;     // combined K for fused [agg|xin] GEMM
constexpr int CAP     = 64;      // bucket capacity per node
constexpr int NXCD    = 8;
constexpr int NPX     = N_NODES / NXCD;   // 12800 nodes per XCD partition (scatter)
constexpr int SGRP    = 104;              // blocks per XCD group for xcd_scatter

using short8 = __attribute__((ext_vector_type(8))) short;
using f32x4  = __attribute__((ext_vector_type(4))) float;

__device__ __forceinline__ short f2bf(float f) {      // RNE float->bf16 bits
    unsigned u = __float_as_uint(f);
    u += 0x7FFFu + ((u >> 16) & 1u);
    return (short)(u >> 16);
}
__device__ __forceinline__ float bf2f(short s) {
    return __uint_as_float(((unsigned)(unsigned short)s) << 16);
}

// ---------------- fused small weight prep (5 transposes + 2 bf16 precasts) ----------------
__device__ __forceinline__ void tr_seg(const float* __restrict__ in, float* __restrict__ out,
                                       int R, int C, int i) {
    if (i < R * C) {
        int r = i / C, c = i % C;
        out[(long)c * R + r] = in[i];
    }
}
__device__ __forceinline__ void wbt_seg(const float* __restrict__ Wrel, const float* __restrict__ Wroot,
                                        short* __restrict__ WBT, int i) {
    if (i < H * KCOMB) {
        int h = i >> 8, k = i & 255;
        float v = (k < H) ? Wrel[k * H + h] : Wroot[(k - H) * H + h];
        WBT[h * KCOMB + k] = f2bf(v);
    }
}
constexpr int PB0 = 126;   // Wc   (128,252)T
constexpr int PB1 = 180;   // Wihf (360,128)T
constexpr int PB2 = 180;   // Wihb
constexpr int PB3 = 169;   // Whhf (360,120)T
constexpr int PB4 = 169;   // Whhb
constexpr int PB6 = 128;   // WBT2
constexpr int PB7 = 128;   // WBT3
constexpr int PREP_BLOCKS = PB0+PB1+PB2+PB3+PB4+PB6+PB7;

__global__ void prep_fused(const float* Wc, float* WCT,
                           const float* Wihf, float* WIHTF,
                           const float* Wihb, float* WIHTB,
                           const float* Whhf, float* WHHTF,
                           const float* Whhb, float* WHHTB,
                           const float* W2rel, const float* W2root, short* WBT2,
                           const float* W3rel, const float* W3root, short* WBT3) {
    int b = blockIdx.x;
    int t = threadIdx.x;
    if (b < PB0) { tr_seg(Wc,   WCT,   128, 252, b * 256 + t); return; }  b -= PB0;
    if (b < PB1) { tr_seg(Wihf, WIHTF, G3,  H,   b * 256 + t); return; }  b -= PB1;
    if (b < PB2) { tr_seg(Wihb, WIHTB, G3,  H,   b * 256 + t); return; }  b -= PB2;
    if (b < PB3) { tr_seg(Whhf, WHHTF, G3,  GH,  b * 256 + t); return; }  b -= PB3;
    if (b < PB4) { tr_seg(Whhb, WHHTB, G3,  GH,  b * 256 + t); return; }  b -= PB4;
    if (b < PB6) { wbt_seg(W2rel, W2root, WBT2, b * 256 + t); return; }   b -= PB6;
    wbt_seg(W3rel, W3root, WBT3, b * 256 + t);
}

// ---------------- LDS-tiled transpose for Wd1 (4816,102) -> (102,4816) ----------------
__global__ __launch_bounds__(256) void transpose_tiled(const float* __restrict__ in,
                                                       float* __restrict__ out, int R, int C) {
    __shared__ float tile[32][33];
    const int rb = blockIdx.x * 32, cb = blockIdx.y * 32;
    const int tx = threadIdx.x & 31, ty = threadIdx.x >> 5;   // 32 x 8
#pragma unroll
    for (int yy = 0; yy < 32; yy += 8) {
        int r = rb + ty + yy, c = cb + tx;
        if (r < R && c < C) tile[ty + yy][tx] = in[(long)r * C + c];
    }
    __syncthreads();
#pragma unroll
    for (int yy = 0; yy < 32; yy += 8) {
        int ro = cb + ty + yy, co = rb + tx;
        if (ro < C && co < R) out[(long)ro * R + co] = tile[tx][ty + yy];
    }
}

// ================= FUSED: xcd_scatter [0,832) + conv1d_pool [832,832+2432) =================
constexpr int SCB = NXCD * SGRP;            // 832 scatter blocks (keeps blockIdx&7 pattern)
constexpr int C1B = (TT * BGR) / 2;         // 2432 conv1d blocks (2 (p,b) pairs each)

__global__ __launch_bounds__(256) void scatter_conv1d(
        const int* __restrict__ src, const int* __restrict__ dst,
        int* __restrict__ cnt, int* __restrict__ csr, int E,
        const float* __restrict__ tin, const float* __restrict__ WcT,
        const float* __restrict__ bc, float* __restrict__ xs) {
    if (blockIdx.x < SCB) {
        // ---- XCD-partitioned scatter (r10-verified) ----
        const int g   = blockIdx.x & (NXCD - 1);
        const int grp = blockIdx.x >> 3;
        const int nlo = g * NPX, nhi = nlo + NPX;
        const int stride = SGRP * 256 * 4;
        for (int e = (grp * 256 + threadIdx.x) * 4; e + 3 < E; e += stride) {
            const int4 s = *(const int4*)(src + e);
            const int4 d = *(const int4*)(dst + e);
            if (d.x >= nlo && d.x < nhi) { int p = atomicAdd(&cnt[d.x], 1); csr[((long)d.x << 6) + p] = s.x; }
            if (d.y >= nlo && d.y < nhi) { int p = atomicAdd(&cnt[d.y], 1); csr[((long)d.y << 6) + p] = s.y; }
            if (d.z >= nlo && d.z < nhi) { int p = atomicAdd(&cnt[d.z], 1); csr[((long)d.z << 6) + p] = s.z; }
            if (d.w >= nlo && d.w < nhi) { int p = atomicAdd(&cnt[d.w], 1); csr[((long)d.w << 6) + p] = s.w; }
        }
        return;
    }
    // ---- conv1d(84->128,k=3)+relu+avgpool5, 2 (p,b) pairs per block ----
    __shared__ float sIn[2][C_IN][8];
    const int half = threadIdx.x >> 7;      // 0..1
    const int o    = threadIdx.x & 127;
    const int id   = (blockIdx.x - SCB) * 2 + half;   // 0..4863
    const int p = id / BGR, b = id % BGR;
    const float* ib = tin + (long)b * C_IN * LSEQ;
    for (int idx = o; idx < C_IN * 7; idx += 128) {
        int c = idx / 7, j = idx % 7;
        sIn[half][c][j] = ib[c * LSEQ + 5 * p + j];
    }
    __syncthreads();
    float a0 = 0, a1 = 0, a2 = 0, a3 = 0, a4 = 0;
    for (int c = 0; c < C_IN; ++c) {
        float i0 = sIn[half][c][0], i1 = sIn[half][c][1], i2 = sIn[half][c][2], i3 = sIn[half][c][3];
        float i4 = sIn[half][c][4], i5 = sIn[half][c][5], i6 = sIn[half][c][6];
        float w0 = WcT[(c * 3 + 0) * H + o];
        float w1 = WcT[(c * 3 + 1) * H + o];
        float w2 = WcT[(c * 3 + 2) * H + o];
        a0 += w0 * i0 + w1 * i1 + w2 * i2;
        a1 += w0 * i1 + w1 * i2 + w2 * i3;
        a2 += w0 * i2 + w1 * i3 + w2 * i4;
        a3 += w0 * i3 + w1 * i4 + w2 * i5;
        a4 += w0 * i4 + w1 * i5 + w2 * i6;
    }
    float bcv = bc[o];
    float r = fmaxf(a0 + bcv, 0.f) + fmaxf(a1 + bcv, 0.f) + fmaxf(a2 + bcv, 0.f)
            + fmaxf(a3 + bcv, 0.f) + fmaxf(a4 + bcv, 0.f);
    xs[((long)p * BGR + b) * H + o] = r * 0.2f;
}

// ================= FUSED: agg4_csr + gi_gemm(F) + gi_gemm(B), 384 threads =================
constexpr int A4B = (N_NODES * 4 + 383) / 384;   // 1067
constexpr int GIB_ = (TT * BGR) / 16;            // 304 per direction

__device__ __forceinline__ void gi_body(const float* __restrict__ xs,
                                        const float* __restrict__ WihT,
                                        const float* __restrict__ bih,
                                        float* __restrict__ gi, int bid) {
    const long r0 = (long)bid * 16;
    const int g = threadIdx.x;
    __shared__ __align__(16) float sX[16][H];
    for (int idx = threadIdx.x; idx < 16 * H; idx += 384)
        sX[idx >> 7][idx & (H - 1)] = xs[r0 * H + idx];
    __syncthreads();
    if (g >= G3) return;
    const float bv = bih[g];
    float acc[16];
#pragma unroll
    for (int r = 0; r < 16; ++r) acc[r] = bv;
    for (int k = 0; k < H; k += 4) {
        float w0 = WihT[(k + 0) * G3 + g], w1 = WihT[(k + 1) * G3 + g];
        float w2 = WihT[(k + 2) * G3 + g], w3 = WihT[(k + 3) * G3 + g];
#pragma unroll
        for (int r = 0; r < 16; ++r) {
            float4 xv = *(const float4*)&sX[r][k];
            acc[r] += xv.x * w0 + xv.y * w1 + xv.z * w2 + xv.w * w3;
        }
    }
#pragma unroll
    for (int r = 0; r < 16; ++r)
        gi[(r0 + r) * G3 + g] = acc[r];
}

__global__ __launch_bounds__(384) void agg4_gi(
        const int* __restrict__ cnt, const int* __restrict__ csr,
        const float* __restrict__ x, float* __restrict__ agg,
        const float* __restrict__ xs,
        const float* __restrict__ WihTF, const float* __restrict__ bihF, float* __restrict__ giF,
        const float* __restrict__ WihTB, const float* __restrict__ bihB, float* __restrict__ giB) {
    int b = blockIdx.x;
    if (b < A4B) {
        int i = b * 384 + threadIdx.x;
        if (i < N_NODES * 4) {
            int n = i >> 2, c = i & 3;
            const int cn = cnt[n];
            const int* idx = csr + ((long)n << 6);
            float acc = 0.f;
            for (int j = 0; j < cn; ++j) acc += x[(long)idx[j] * 4 + c];
            agg[i] = acc;
        }
        return;
    }
    b -= A4B;
    if (b < GIB_) { gi_body(xs, WihTF, bihF, giF, b); return; }
    b -= GIB_;
    gi_body(xs, WihTB, bihB, giB, b);
}

// ================= conv1 transform: fp32 out + bf16 copy =================
__global__ void gc1_transform(const float* __restrict__ agg4, const float* __restrict__ x,
                              const float* __restrict__ Wrel, const float* __restrict__ Wroot,
                              const float* __restrict__ bias, float* __restrict__ out,
                              short* __restrict__ outb) {
    long i = (long)blockIdx.x * 256 + threadIdx.x;   // over N*H
    int h = (int)(i & (H - 1));
    long n = i >> 7;
    const float4 a  = *(const float4*)(agg4 + n * 4);
    const float4 xv = *(const float4*)(x    + n * 4);
    float acc = bias[h]
        + a.x  * Wrel[0 * H + h] + a.y  * Wrel[1 * H + h]
        + a.z  * Wrel[2 * H + h] + a.w  * Wrel[3 * H + h]
        + xv.x * Wroot[0 * H + h] + xv.y * Wroot[1 * H + h]
        + xv.z * Wroot[2 * H + h] + xv.w * Wroot[3 * H + h];
    float v = fmaxf(acc, 0.f);
    out[i] = v;
    outb[i] = f2bf(v);
}

// ================= bf16 CSR gather (r13-verified, 8-deep unroll) =================
__global__ __launch_bounds__(256) void agg128_bf(const int* __restrict__ cnt,
                                                 const int* __restrict__ csr,
                                                 const short* __restrict__ xb,
                                                 short* __restrict__ aggb) {
    const int lane = threadIdx.x & 15;          // 8 bf16 columns each
    const int n = blockIdx.x * 16 + (threadIdx.x >> 4);
    const int cn = cnt[n];
    const int* idx = csr + ((long)n << 6);
    const short* xs = xb + lane * 8;
    float acc[8];
#pragma unroll
    for (int q = 0; q < 8; ++q) acc[q] = 0.f;
    int j = 0;
    for (; j + 7 < cn; j += 8) {
        const int4 i0 = *(const int4*)(idx + j);
        const int4 i1 = *(const int4*)(idx + j + 4);
        const short8 r0 = *(const short8*)(xs + (long)i0.x * H);
        const short8 r1 = *(const short8*)(xs + (long)i0.y * H);
        const short8 r2 = *(const short8*)(xs + (long)i0.z * H);
        const short8 r3 = *(const short8*)(xs + (long)i0.w * H);
        const short8 r4 = *(const short8*)(xs + (long)i1.x * H);
        const short8 r5 = *(const short8*)(xs + (long)i1.y * H);
        const short8 r6 = *(const short8*)(xs + (long)i1.z * H);
        const short8 r7 = *(const short8*)(xs + (long)i1.w * H);
#pragma unroll
        for (int q = 0; q < 8; ++q)
            acc[q] += ((bf2f(r0[q]) + bf2f(r1[q])) + (bf2f(r2[q]) + bf2f(r3[q])))
                    + ((bf2f(r4[q]) + bf2f(r5[q])) + (bf2f(r6[q]) + bf2f(r7[q])));
    }
    for (; j + 3 < cn; j += 4) {
        const int4 ii = *(const int4*)(idx + j);
        const short8 r0 = *(const short8*)(xs + (long)ii.x * H);
        const short8 r1 = *(const short8*)(xs + (long)ii.y * H);
        const short8 r2 = *(const short8*)(xs + (long)ii.z * H);
        const short8 r3 = *(const short8*)(xs + (long)ii.w * H);
#pragma unroll
        for (int q = 0; q < 8; ++q)
            acc[q] += (bf2f(r0[q]) + bf2f(r1[q])) + (bf2f(r2[q]) + bf2f(r3[q]));
    }
    for (; j < cn; ++j) {
        const short8 r0 = *(const short8*)(xs + (long)idx[j] * H);
#pragma unroll
        for (int q = 0; q < 8; ++q) acc[q] += bf2f(r0[q]);
    }
    short8 o;
#pragma unroll
    for (int q = 0; q < 8; ++q) o[q] = f2bf(acc[q]);
    *(short8*)(aggb + (long)n * H + lane * 8) = o;
}

// ---------------- standalone BiGRU recurrence (r13-verified; fusing it spilled, r14) ----------------
__device__ __forceinline__ float sigmoidf_(float x) { return 1.f / (1.f + expf(-x)); }

__global__ __launch_bounds__(384) void gru_kernel(
        const float* __restrict__ giF, const float* __restrict__ giB,
        const float* __restrict__ WhhTF, const float* __restrict__ WhhTB,
        const float* __restrict__ bhhF, const float* __restrict__ bhhB,
        float* __restrict__ xc) {
    const int b = blockIdx.x & (BGR - 1);
    const int dir = blockIdx.x >> 8;
    const float* gi   = dir ? giB : giF;
    const float* WhhT = dir ? WhhTB : WhhTF;
    const float* bhh  = dir ? bhhB : bhhF;
    const int g = threadIdx.x;
    const int gc = g < G3 ? g : (G3 - 1);

    float w[GH];
#pragma unroll
    for (int k = 0; k < GH; ++k) w[k] = WhhT[(long)k * G3 + gc];
    const float bh = bhh[gc];

    __shared__ __align__(16) float sh[GH];
    __shared__ float sgh[G3];
    if (g < GH) sh[g] = 0.f;
    __syncthreads();

    for (int tt = 0; tt < TT; ++tt) {
        const int t = dir ? (TT - 1 - tt) : tt;
        float acc = bh;
#pragma unroll
        for (int k4 = 0; k4 < GH / 4; ++k4) {
            float4 hv = *(const float4*)&sh[k4 * 4];
            acc += hv.x * w[k4 * 4] + hv.y * w[k4 * 4 + 1]
                 + hv.z * w[k4 * 4 + 2] + hv.w * w[k4 * 4 + 3];
        }
        if (g < G3) sgh[g] = acc;
        __syncthreads();
        if (g < GH) {
            const float* gib = gi + ((long)t * BGR + b) * G3;
            float r = sigmoidf_(gib[g] + sgh[g]);
            float z = sigmoidf_(gib[GH + g] + sgh[GH + g]);
            float n = tanhf(gib[2 * GH + g] + r * sgh[2 * GH + g]);
            float h2 = (1.f - z) * n + z * sh[g];
            sh[g] = h2;
            xc[(long)b * DHEAD + 256 + t * 240 + dir * GH + g] = h2;
        }
        __syncthreads();
    }
}

// ---------------- GraphConv node transform via bf16 MFMA ----------------
template <int RES, int OUTF, int OUTB>
__global__ __launch_bounds__(256) void gc_mfma(
        const short* __restrict__ aggb, const short* __restrict__ xinb,
        const short* __restrict__ WBT, const float* __restrict__ bias,
        const float* __restrict__ res, float* __restrict__ outf,
        short* __restrict__ outb) {
    const int wid   = threadIdx.x >> 6;     // 0..3
    const int lane  = threadIdx.x & 63;
    const int l15   = lane & 15;
    const int kslot = lane >> 4;            // 0..3
    const long n0   = (long)blockIdx.x * 128 + wid * 32;

    f32x4 acc[2][8];
#pragma unroll
    for (int i = 0; i < 2; ++i)
#pragma unroll
        for (int j = 0; j < 8; ++j) acc[i][j] = (f32x4){0.f, 0.f, 0.f, 0.f};

#pragma unroll
    for (int ks = 0; ks < 8; ++ks) {        // combined-k step of 32
        const short* srcb = (ks < 4) ? aggb : xinb;
        const int koff = (ks < 4 ? ks * 32 : (ks - 4) * 32) + kslot * 8;
        short8 afr[2];
#pragma unroll
        for (int rt = 0; rt < 2; ++rt)
            afr[rt] = *(const short8*)(srcb + (n0 + rt * 16 + l15) * H + koff);
        const int kb = ks * 32 + kslot * 8;
        short8 bfr[8];
#pragma unroll
        for (int ct = 0; ct < 8; ++ct)
            bfr[ct] = *(const short8*)(WBT + (long)(ct * 16 + l15) * KCOMB + kb);
#pragma unroll
        for (int rt = 0; rt < 2; ++rt)
#pragma unroll
            for (int ct = 0; ct < 8; ++ct)
                acc[rt][ct] = __builtin_amdgcn_mfma_f32_16x16x32_bf16(
                    afr[rt], bfr[ct], acc[rt][ct], 0, 0, 0);
    }

#pragma unroll
    for (int rt = 0; rt < 2; ++rt) {
        const long rbase = n0 + rt * 16 + kslot * 4;
#pragma unroll
        for (int ct = 0; ct < 8; ++ct) {
            const int h = ct * 16 + l15;
            const float bv = bias[h];
#pragma unroll
            for (int r = 0; r < 4; ++r) {
                const long rowi = rbase + r;
                float v = fmaxf(acc[rt][ct][r] + bv, 0.f);
                if (RES) v += res[rowi * H + h];
                if (OUTF) outf[rowi * H + h] = v;
                if (OUTB) outb[rowi * H + h] = f2bf(v);
            }
        }
    }
}

// ---------------- graph max/mean pool -> xc[:, 0:256] ----------------
__global__ __launch_bounds__(512) void pool_kernel(const float* __restrict__ x4, float* __restrict__ xc) {
    int g = blockIdx.x;
    int h = threadIdx.x & 127;
    int part = threadIdx.x >> 7;        // 0..3 (100 nodes each)
    const float* base = x4 + ((long)g * NPG + part * 100) * H + h;
    float mx = -INFINITY, sm = 0.f;
#pragma unroll 4
    for (int i = 0; i < 100; ++i) {
        float v = base[(long)i * H];
        mx = fmaxf(mx, v);
        sm += v;
    }
    __shared__ float smx[4][128], ssm[4][128];
    smx[part][h] = mx; ssm[part][h] = sm;
    __syncthreads();
    if (part == 0) {
        float m = fmaxf(fmaxf(smx[0][h], smx[1][h]), fmaxf(smx[2][h], smx[3][h]));
        float s = ssm[0][h] + ssm[1][h] + ssm[2][h] + ssm[3][h];
        xc[(long)g * DHEAD + h] = m;
        xc[(long)g * DHEAD + H + h] = s * (1.f / NPG);
    }
}

// ---------------- dense head: 2-way k-split, atomic partials into zeroed D1 ----------------
__global__ __launch_bounds__(256) void dense1(const float* __restrict__ xc,
                                              const float* __restrict__ Wd1T,
                                              float* __restrict__ d1) {
    const int wid0 = blockIdx.x * 4 + (threadIdx.x >> 6);   // 0 .. 26*32*2-1
    const int lane = threadIdx.x & 63;
    const int ks   = wid0 & 1;              // k-split half
    const int wid  = wid0 >> 1;
    const int jg = wid % 26;
    const int bg = wid / 26;
    const int j0 = jg * 4, b0 = bg * 8;
    const int i0 = ks * 602, i1 = i0 + 602;  // float4 index range (1204 total)

    float acc[4][8];
#pragma unroll
    for (int jj = 0; jj < 4; ++jj)
#pragma unroll
        for (int bb = 0; bb < 8; ++bb) acc[jj][bb] = 0.f;

    for (int i = i0 + lane; i < i1; i += 64) {
        float4 wv[4], xv[8];
#pragma unroll
        for (int jj = 0; jj < 4; ++jj) {
            int j = j0 + jj; if (j > D1O - 1) j = D1O - 1;
            wv[jj] = *(const float4*)(Wd1T + (long)j * DHEAD + i * 4);
        }
#pragma unroll
        for (int bb = 0; bb < 8; ++bb)
            xv[bb] = *(const float4*)(xc + (long)(b0 + bb) * DHEAD + i * 4);
#pragma unroll
        for (int jj = 0; jj < 4; ++jj)
#pragma unroll
            for (int bb = 0; bb < 8; ++bb)
                acc[jj][bb] += wv[jj].x * xv[bb].x + wv[jj].y * xv[bb].y
                             + wv[jj].z * xv[bb].z + wv[jj].w * xv[bb].w;
    }
#pragma unroll
    for (int m = 32; m >= 1; m >>= 1)
#pragma unroll
        for (int jj = 0; jj < 4; ++jj)
#pragma unroll
            for (int bb = 0; bb < 8; ++bb)
                acc[jj][bb] += __shfl_xor(acc[jj][bb], m, 64);
    if (lane < 32) {
        const int jj = lane >> 3, bb = lane & 7;
        const int j = j0 + jj;
        if (j < D1O)
            atomicAdd(&d1[(long)(b0 + bb) * D1O + j], acc[jj][bb]);
    }
}

// bias+relu folded here (d1 holds raw partial sums)
__global__ void final_head(const float* __restrict__ d1, const float* __restrict__ bd1,
                           const float* __restrict__ Wd3, const float* __restrict__ bd3,
                           float* __restrict__ out) {
    int b = threadIdx.x;   // 256 threads, 1 block
    if (b >= BGR) return;
    float v0 = bd3[0], v1 = bd3[1];
    for (int k = 0; k < D1O; ++k) {
        float xv = fmaxf(d1[(long)b * D1O + k] + bd1[k], 0.f);
        v0 += xv * Wd3[k * 2 + 0];
        v1 += xv * Wd3[k * 2 + 1];
    }
    float m = fmaxf(v0, v1);
    float lse = m + logf(expf(v0 - m) + expf(v1 - m));
    out[b * 2 + 0] = v0 - lse;
    out[b * 2 + 1] = v1 - lse;
}

// ---------------- launch ----------------
extern "C" void kernel_launch(void* const* d_in, const int* in_sizes, int n_in,
                              void* d_out, int out_size, void* d_ws, size_t ws_size,
                              hipStream_t stream) {
    const float* x      = (const float*)d_in[0];
    const int*   ei     = (const int*)d_in[1];
    const float* tgt    = (const float*)d_in[3];
    const float* W1rel  = (const float*)d_in[4];
    const float* W1root = (const float*)d_in[5];
    const float* b1     = (const float*)d_in[6];
    const float* W2rel  = (const float*)d_in[7];
    const float* W2root = (const float*)d_in[8];
    const float* b2     = (const float*)d_in[9];
    const float* W3rel  = (const float*)d_in[10];
    const float* W3root = (const float*)d_in[11];
    const float* b3     = (const float*)d_in[12];
    const float* Wc     = (const float*)d_in[13];
    const float* bc     = (const float*)d_in[14];
    const float* Wih_f  = (const float*)d_in[15];
    const float* Whh_f  = (const float*)d_in[16];
    const float* bih_f  = (const float*)d_in[17];
    const float* bhh_f  = (const float*)d_in[18];
    const float* Wih_b  = (const float*)d_in[19];
    const float* Whh_b  = (const float*)d_in[20];
    const float* bih_b  = (const float*)d_in[21];
    const float* bhh_b  = (const float*)d_in[22];
    const float* Wd1    = (const float*)d_in[23];
    const float* bd1    = (const float*)d_in[24];
    const float* Wd3    = (const float*)d_in[25];
    const float* bd3    = (const float*)d_in[26];

    const int* srcI = ei;
    const int* dstI = ei + N_EDGES;

    // workspace layout (floats)
    float* ws = (float*)d_ws;
    size_t off = 0;
    float* AGG4  = ws + off; off += (size_t)N_NODES * 4;
    float* X1    = ws + off; off += (size_t)N_NODES * H;   // fp32: residual src, conv4 out
    float* XS    = ws + off; off += (size_t)TT * BGR * H;
    float* GIF   = ws + off; off += (size_t)TT * BGR * G3;
    float* GIB   = ws + off; off += (size_t)TT * BGR * G3;
    float* XC    = ws + off; off += (size_t)BGR * DHEAD;
    float* D1    = ws + off; off += (size_t)BGR * D1O + 2;
    float* WCT   = ws + off; off += (size_t)C_IN * 3 * H;
    float* WIHTF = ws + off; off += (size_t)H * G3;
    float* WIHTB = ws + off; off += (size_t)H * G3;
    float* WHHTF = ws + off; off += (size_t)GH * G3;
    float* WHHTB = ws + off; off += (size_t)GH * G3;
    float* WD1T  = ws + off; off += (size_t)DHEAD * D1O;
    off = (off + 3) & ~(size_t)3;                       // 16B align
    short* WBT2  = (short*)(ws + off); off += (size_t)H * KCOMB / 2;   // bf16 [128][256]
    short* WBT3  = (short*)(ws + off); off += (size_t)H * KCOMB / 2;
    short* AGGB  = (short*)(ws + off); off += (size_t)N_NODES * H / 2; // bf16 agg
    short* X1B   = (short*)(ws + off); off += (size_t)N_NODES * H / 2; // bf16 x1
    short* X2B   = (short*)(ws + off); off += (size_t)N_NODES * H / 2; // bf16 x2
    short* X3B   = (short*)(ws + off); off += (size_t)N_NODES * H / 2; // bf16 x3
    // int region
    int* ibase   = (int*)(ws + off);
    int* CNT     = ibase;                     // N
    int* CSR     = ibase + N_NODES;           // N * CAP

    // weight prep
    prep_fused<<<PREP_BLOCKS, 256, 0, stream>>>(Wc, WCT, Wih_f, WIHTF, Wih_b, WIHTB,
                                                Whh_f, WHHTF, Whh_b, WHHTB,
                                                W2rel, W2root, WBT2, W3rel, W3root, WBT3);
    transpose_tiled<<<dim3((DHEAD + 31) / 32, (D1O + 31) / 32), 256, 0, stream>>>(Wd1, WD1T, DHEAD, D1O);

    // zero CNT + D1 (dense1 accumulates atomically)
    hipMemsetAsync(CNT, 0, (size_t)N_NODES * sizeof(int), stream);
    hipMemsetAsync(D1, 0, (size_t)BGR * D1O * sizeof(float), stream);

    // ---- FUSED: XCD scatter || conv1d+pool ----
    scatter_conv1d<<<SCB + C1B, 256, 0, stream>>>(srcI, dstI, CNT, CSR, N_EDGES,
                                                  tgt, WCT, bc, XS);

    // ---- FUSED: conv1 aggregation || gi GEMMs ----
    agg4_gi<<<A4B + 2 * GIB_, 384, 0, stream>>>(CNT, CSR, x, AGG4, XS,
                                                WIHTF, bih_f, GIF, WIHTB, bih_b, GIB);

    // conv1 transform: fp32 + bf16 copy
    gc1_transform<<<(N_NODES * H) / 256, 256, 0, stream>>>(AGG4, x, W1rel, W1root, b1, X1, X1B);

    // BiGRU (standalone: fusing with the gather spilled registers, r14)
    gru_kernel<<<2 * BGR, 384, 0, stream>>>(GIF, GIB, WHHTF, WHHTB, bhh_f, bhh_b, XC);

    // conv2: x1 -> x2 (bf16 only)
    agg128_bf<<<N_NODES / 16, 256, 0, stream>>>(CNT, CSR, X1B, AGGB);
    gc_mfma<0, 0, 1><<<N_NODES / 128, 256, 0, stream>>>(AGGB, X1B, WBT2, b2, nullptr, nullptr, X2B);

    // conv3: x2 -> x3 (bf16 only), + residual x1 (fp32)
    agg128_bf<<<N_NODES / 16, 256, 0, stream>>>(CNT, CSR, X2B, AGGB);
    gc_mfma<1, 0, 1><<<N_NODES / 128, 256, 0, stream>>>(AGGB, X2B, WBT3, b3, X1, nullptr, X3B);

    // conv4: x3 -> x4 (fp32, reuses X1)
    agg128_bf<<<N_NODES / 16, 256, 0, stream>>>(CNT, CSR, X3B, AGGB);
    gc_mfma<0, 1, 0><<<N_NODES / 128, 256, 0, stream>>>(AGGB, X3B, WBT3, b3, nullptr, X1, nullptr);

    // pooling -> xc[:, 0:256]
    pool_kernel<<<BGR, 512, 0, stream>>>(X1, XC);

    // dense head (k-split atomic) + final
    dense1<<<(26 * 32 * 2) / 4, 256, 0, stream>>>(XC, WD1T, D1);
    final_head<<<1, 256, 0, stream>>>(D1, bd1, Wd3, bd3, (float*)d_out);
}